// Round 7
// baseline (1166.501 us; speedup 1.0000x reference)
//
#include <hip/hip_runtime.h>
#include <hip/hip_fp16.h>
#include <math.h>

// Problem constants (fixed by the reference)
constexpr int N    = 50000;
constexpr int E    = 1600000;
constexpr int FD   = 128;   // feature dim (in and out of both GAT layers)
constexpr int H    = 4;     // heads
constexpr int G    = 64;    // graphs
constexpr int NCH  = 16;    // node-chunks per graph for parallel reductions
constexpr int OUT  = 10;

// CSR-build partition parameters
constexpr int NBIN   = (N + 255) / 256;        // 196 bins of 256 nodes (bin = dst>>8)
constexpr int EPB    = 4096;                   // edges per partition block
constexpr int NBLK_E = (E + EPB - 1) / EPB;    // 391

#define DEV __device__ __forceinline__

DEV void fma4(float4& a, float s, const float4& w) {
    a.x = fmaf(s, w.x, a.x); a.y = fmaf(s, w.y, a.y);
    a.z = fmaf(s, w.z, a.z); a.w = fmaf(s, w.w, a.w);
}

DEV float lrelu_exp(float z) {             // exp(leaky_relu(z, 0.2))
    return __expf(z > 0.f ? z : 0.2f * z);
}

union HF4 {                                // 4 halfs <-> one 8B word
    float2  f;
    __half2 h[2];
};

DEV void fmah(float4& a, float w, const HF4& u) {
    float2 lo = __half22float2(u.h[0]);
    float2 hi = __half22float2(u.h[1]);
    a.x = fmaf(w, lo.x, a.x); a.y = fmaf(w, lo.y, a.y);
    a.z = fmaf(w, hi.x, a.z); a.w = fmaf(w, hi.y, a.w);
}

DEV float4 load4f(const float* p) { return *(const float4*)p; }
DEV float4 load4f(const __half* p) {
    HF4 u; u.f = *(const float2*)p;
    float2 lo = __half22float2(u.h[0]);
    float2 hi = __half22float2(u.h[1]);
    return make_float4(lo.x, lo.y, hi.x, hi.y);
}

// ---------------- setup kernels ----------------

__global__ void k_zero(int* __restrict__ hist, float* __restrict__ hg,
                       float* __restrict__ S1, float* __restrict__ S2,
                       float* __restrict__ Eg1, float* __restrict__ Eg2) {
    int i = blockIdx.x * 256 + threadIdx.x;
    if (i < NBIN) hist[i] = 0;
    if (i < G * FD) { hg[i] = 0.f; S1[i] = 0.f; S2[i] = 0.f; }
    if (i < G) { Eg1[i] = 0.f; Eg2[i] = 0.f; }
}

__global__ void k_graph_starts(const int* __restrict__ batch, int* __restrict__ gs) {
    int i = blockIdx.x * 256 + threadIdx.x;
    if (i >= N) return;
    int b  = batch[i];
    int pb = (i == 0) ? -1 : batch[i - 1];
    for (int g = pb + 1; g <= b; ++g) gs[g] = i;
    if (i == N - 1) for (int g = b + 1; g <= G; ++g) gs[g] = N;
}

// Coarse histogram: 196 bins, LDS-aggregated.
__global__ __launch_bounds__(256)
void k_hist(const int* __restrict__ dst, int* __restrict__ hist) {
    __shared__ int lh[NBIN];
    int t = threadIdx.x;
    for (int i = t; i < NBIN; i += 256) lh[i] = 0;
    __syncthreads();
    int base = blockIdx.x * EPB;
#pragma unroll
    for (int j = 0; j < EPB / 256; ++j) {
        int e = base + j * 256 + t;
        if (e < E) atomicAdd(&lh[dst[e] >> 8], 1);
    }
    __syncthreads();
    for (int i = t; i < NBIN; i += 256) if (lh[i]) atomicAdd(&hist[i], lh[i]);
}

// Scan bin totals -> bin bases + partition cursors; also off[N]=E.
__global__ __launch_bounds__(256)
void k_binscan(const int* __restrict__ hist, int* __restrict__ binbase,
               int* __restrict__ cursor, int* __restrict__ off) {
    __shared__ int sh[256];
    int t = threadIdx.x;
    int v = (t < NBIN) ? hist[t] : 0;
    sh[t] = v;
    __syncthreads();
    for (int d = 1; d < 256; d <<= 1) {
        int add = (t >= d) ? sh[t - d] : 0;
        __syncthreads();
        sh[t] += add;
        __syncthreads();
    }
    if (t < NBIN) {
        binbase[t] = sh[t] - v;       // exclusive
        cursor[t]  = sh[t] - v;
    }
    if (t == NBIN - 1) binbase[NBIN] = sh[t];   // == E
    if (t == 0) off[N] = E;
}

// Partition edges into bin-contiguous storage. Pack: src (16b) | dstLocal (8b) << 16.
__global__ __launch_bounds__(256)
void k_partition(const int* __restrict__ src, const int* __restrict__ dst,
                 int* __restrict__ cursor, unsigned int* __restrict__ part) {
    __shared__ int lh[NBIN];
    __shared__ int gb[NBIN];
    int t = threadIdx.x;
    for (int i = t; i < NBIN; i += 256) lh[i] = 0;
    __syncthreads();
    int base = blockIdx.x * EPB;
    unsigned int pk[EPB / 256];
    int          pr[EPB / 256];        // (bin<<16) | rank, or -1
#pragma unroll
    for (int j = 0; j < EPB / 256; ++j) {
        int e = base + j * 256 + t;
        if (e < E) {
            int d = dst[e];
            int b = d >> 8;
            int r = atomicAdd(&lh[b], 1);            // local rank within (block,bin)
            pk[j] = (unsigned)src[e] | ((unsigned)(d & 255) << 16);
            pr[j] = (b << 16) | r;
        } else pr[j] = -1;
    }
    __syncthreads();
    for (int i = t; i < NBIN; i += 256) gb[i] = atomicAdd(&cursor[i], lh[i]);
    __syncthreads();
#pragma unroll
    for (int j = 0; j < EPB / 256; ++j) {
        if (pr[j] >= 0) {
            int b = pr[j] >> 16, r = pr[j] & 0xFFFF;
            part[gb[b] + r] = pk[j];
        }
    }
}

// Fine pass: one block per bin -> per-node CSR offsets + bin-local scatter.
__global__ __launch_bounds__(256)
void k_fine(const unsigned int* __restrict__ part, const int* __restrict__ binbase,
            int* __restrict__ off, int* __restrict__ col) {
    __shared__ int lh[256], lo[256], lc[256];
    int b = blockIdx.x, t = threadIdx.x;
    int s = binbase[b], e = binbase[b + 1];
    lh[t] = 0; lc[t] = 0;
    __syncthreads();
    for (int i = s + t; i < e; i += 256) atomicAdd(&lh[part[i] >> 16], 1);
    __syncthreads();
    int v = lh[t];
    lo[t] = v;
    __syncthreads();
    for (int d = 1; d < 256; d <<= 1) {
        int add = (t >= d) ? lo[t - d] : 0;
        __syncthreads();
        lo[t] += add;
        __syncthreads();
    }
    int ex = lo[t] - v;                 // exclusive scan
    __syncthreads();
    lo[t] = ex;
    __syncthreads();
    int node = b * 256 + t;
    if (node < N) off[node] = s + ex;
    for (int i = s + t; i < e; i += 256) {
        unsigned p = part[i];
        int dl = p >> 16;
        int r = atomicAdd(&lc[dl], 1);
        col[s + lo[dl] + r] = (int)(p & 0xFFFFu);
    }
}

// ---------------- GEMM + attention-logit epilogue ----------------
// Input templated (layer 1: float x, layer 2: fp16 hsm). Output hw fp16.
template <typename TIn>
__global__ __launch_bounds__(256, 2)
void k_gemm_al(const TIn* __restrict__ X, const float* __restrict__ W,
               const float* __restrict__ a_s, const float* __restrict__ a_d,
               __half* __restrict__ hw, float* __restrict__ als, float* __restrict__ ald)
{
    __shared__ float xs[128][128];
    int r0 = blockIdx.x * 128;
    int t  = threadIdx.x;

    for (int i = 0; i < 16; ++i) {
        int f   = i * 256 + t;
        int row = f >> 5;
        int colf = (f & 31) * 4;
        float4 v = make_float4(0.f, 0.f, 0.f, 0.f);
        if (r0 + row < N) v = load4f(X + (size_t)(r0 + row) * FD + colf);
        *(float4*)(&xs[row][colf]) = v;
    }
    __syncthreads();

    int ct = t & 31;
    int rt = t >> 5;
    int c4 = ct * 4;
    int rb = rt * 16;

    float4 acc[16];
#pragma unroll
    for (int r = 0; r < 16; ++r) acc[r] = make_float4(0.f, 0.f, 0.f, 0.f);

    for (int k = 0; k < FD; k += 4) {
        float4 wv0 = *(const float4*)(W + (size_t)(k + 0) * FD + c4);
        float4 wv1 = *(const float4*)(W + (size_t)(k + 1) * FD + c4);
        float4 wv2 = *(const float4*)(W + (size_t)(k + 2) * FD + c4);
        float4 wv3 = *(const float4*)(W + (size_t)(k + 3) * FD + c4);
#pragma unroll
        for (int r = 0; r < 16; ++r) {
            float4 xv = *(const float4*)(&xs[rb + r][k]);
            fma4(acc[r], xv.x, wv0);
            fma4(acc[r], xv.y, wv1);
            fma4(acc[r], xv.z, wv2);
            fma4(acc[r], xv.w, wv3);
        }
    }

    int h  = c4 >> 5;
    int j0 = c4 & 31;
    float as0 = a_s[h * 32 + j0 + 0], as1 = a_s[h * 32 + j0 + 1];
    float as2 = a_s[h * 32 + j0 + 2], as3 = a_s[h * 32 + j0 + 3];
    float ad0 = a_d[h * 32 + j0 + 0], ad1 = a_d[h * 32 + j0 + 1];
    float ad2 = a_d[h * 32 + j0 + 2], ad3 = a_d[h * 32 + j0 + 3];

#pragma unroll
    for (int r = 0; r < 16; ++r) {
        int row = r0 + rb + r;
        bool valid = row < N;
        if (valid) {
            HF4 u;
            u.h[0] = __floats2half2_rn(acc[r].x, acc[r].y);
            u.h[1] = __floats2half2_rn(acc[r].z, acc[r].w);
            *(float2*)(hw + (size_t)row * FD + c4) = u.f;
        }
        float ps = acc[r].x * as0 + acc[r].y * as1 + acc[r].z * as2 + acc[r].w * as3;
        float pd = acc[r].x * ad0 + acc[r].y * ad1 + acc[r].z * ad2 + acc[r].w * ad3;
#pragma unroll
        for (int m = 1; m < 8; m <<= 1) {
            ps += __shfl_xor(ps, m, 64);
            pd += __shfl_xor(pd, m, 64);
        }
        if ((ct & 7) == 0 && valid) {
            als[row * H + h] = ps;
            ald[row * H + h] = pd;
        }
    }
}

// ---------------- fused edge softmax + aggregation ----------------
// One wave per dst node; fp16 rows (256B): 32 lanes x 8B cover one row, so
// the wave processes TWO edges per step (lane halves q=0/1) x4 unrolled ->
// 8 gathers in flight. f32 accumulate; h1 written fp16.
__global__ __launch_bounds__(256)
void k_agg(const __half* __restrict__ hw, const float* __restrict__ als,
           const float* __restrict__ ald, const int* __restrict__ off,
           const int* __restrict__ col, const float* __restrict__ bias,
           __half* __restrict__ h1)
{
    int n = blockIdx.x * 4 + (threadIdx.x >> 6);
    if (n >= N) return;
    int l = threadIdx.x & 63;
    int q = l >> 5;                 // half: edge parity
    int p = l & 31;                 // lane within half: owns cols 4p..4p+3
    int h = p >> 3;                 // head of my columns
    float adn = ald[n * H + h];

    // self-loop: half 0 only
    float4 acc = make_float4(0.f, 0.f, 0.f, 0.f);
    float sumw;
    {
        float w = q ? 0.f : lrelu_exp(als[n * H + h] + adn);
        HF4 u; u.f = *(const float2*)(hw + (size_t)n * FD + 4 * p);
        fmah(acc, w, u);
        sumw = w;
    }

    int ib = off[n];
    int deg = off[n + 1] - ib;
    int j = 0;
    for (; j + 8 <= deg; j += 8) {          // 4 steps x 2 halves
        int s0 = col[ib + j + 0 + q];
        int s1 = col[ib + j + 2 + q];
        int s2 = col[ib + j + 4 + q];
        int s3 = col[ib + j + 6 + q];
        float z0 = als[s0 * H + h];
        float z1 = als[s1 * H + h];
        float z2 = als[s2 * H + h];
        float z3 = als[s3 * H + h];
        HF4 u0; u0.f = *(const float2*)(hw + (size_t)s0 * FD + 4 * p);
        HF4 u1; u1.f = *(const float2*)(hw + (size_t)s1 * FD + 4 * p);
        HF4 u2; u2.f = *(const float2*)(hw + (size_t)s2 * FD + 4 * p);
        HF4 u3; u3.f = *(const float2*)(hw + (size_t)s3 * FD + 4 * p);
        float w0 = lrelu_exp(z0 + adn);
        float w1 = lrelu_exp(z1 + adn);
        float w2 = lrelu_exp(z2 + adn);
        float w3 = lrelu_exp(z3 + adn);
        fmah(acc, w0, u0);
        fmah(acc, w1, u1);
        fmah(acc, w2, u2);
        fmah(acc, w3, u3);
        sumw += w0 + w1 + w2 + w3;
    }
    for (; j + 2 <= deg; j += 2) {          // 1 step x 2 halves
        int s = col[ib + j + q];
        float w = lrelu_exp(als[s * H + h] + adn);
        HF4 u; u.f = *(const float2*)(hw + (size_t)s * FD + 4 * p);
        fmah(acc, w, u);
        sumw += w;
    }
    if (j < deg) {                          // odd leftover: half 0 only
        int s = q ? n : col[ib + j];
        float w = q ? 0.f : lrelu_exp(als[s * H + h] + adn);
        HF4 u; u.f = *(const float2*)(hw + (size_t)s * FD + 4 * p);
        fmah(acc, w, u);
        sumw += w;
    }

    // merge halves (lane l <-> l+32 hold the same columns)
    acc.x += __shfl_xor(acc.x, 32, 64);
    acc.y += __shfl_xor(acc.y, 32, 64);
    acc.z += __shfl_xor(acc.z, 32, 64);
    acc.w += __shfl_xor(acc.w, 32, 64);
    sumw  += __shfl_xor(sumw,  32, 64);

    if (q == 0) {
        float inv = 1.f / sumw;
        float4 b4 = *(const float4*)(bias + 4 * p);
        float4 o;
        o.x = fmaf(acc.x, inv, b4.x);
        o.y = fmaf(acc.y, inv, b4.y);
        o.z = fmaf(acc.z, inv, b4.z);
        o.w = fmaf(acc.w, inv, b4.w);
        o.x = o.x > 0.f ? o.x : 0.f;
        o.y = o.y > 0.f ? o.y : 0.f;
        o.z = o.z > 0.f ? o.z : 0.f;
        o.w = o.w > 0.f ? o.w : 0.f;
        HF4 u;
        u.h[0] = __floats2half2_rn(o.x, o.y);
        u.h[1] = __floats2half2_rn(o.z, o.w);
        *(float2*)(h1 + (size_t)n * FD + 4 * p) = u.f;
    }
}

// ---------------- per-graph column exp-sums (no max-shift; h1 >= 0 bounded) ----------------
__global__ __launch_bounds__(256)
void k_colsum(const __half* __restrict__ h1, const int* __restrict__ gs,
              float* __restrict__ S)
{
    int g = blockIdx.x, ch = blockIdx.y;
    int t = threadIdx.x;
    int c = t & 127, hf = t >> 7;
    int s = gs[g], e = gs[g + 1];
    int per = (e - s + NCH - 1) / NCH;
    int ns = s + ch * per;
    int ne = min(ns + per, e);
    float sum = 0.f;
    for (int n = ns + hf; n < ne; n += 2)
        sum += __expf(__half2float(h1[(size_t)n * FD + c]));
    if (sum > 0.f) atomicAdd(&S[g * FD + c], sum);
}

// ---------------- node softmax-normalize + gate exp (fused gate stats) ----------------
__global__ __launch_bounds__(256)
void k_softmax_gate(const __half* __restrict__ h1, const int* __restrict__ batch,
                    const float* __restrict__ S, const float* __restrict__ gw,
                    const float* __restrict__ gb, __half* __restrict__ hsm,
                    float* __restrict__ egl, float* __restrict__ Eg)
{
    int n = blockIdx.x * 4 + (threadIdx.x >> 6);
    if (n >= N) return;
    int l = threadIdx.x & 63;
    int g = batch[n];
    float2 hv = __half22float2(*(const __half2*)(h1 + (size_t)n * FD + 2 * l));
    float2 sv = *(const float2*)(S + g * FD + 2 * l);
    float vx = __expf(hv.x) / sv.x;
    float vy = __expf(hv.y) / sv.y;
    *(__half2*)(hsm + (size_t)n * FD + 2 * l) = __floats2half2_rn(vx, vy);
    float p = vx * gw[2 * l] + vy * gw[2 * l + 1];
#pragma unroll
    for (int m = 1; m < 64; m <<= 1) p += __shfl_xor(p, m, 64);
    if (l == 0) {
        float eg = __expf(p + gb[0]);     // no max-shift: p is tiny
        egl[n] = eg;
        atomicAdd(&Eg[g], eg);
    }
}

// ---------------- gated pooling (chunked, atomic accumulate into hg) ----------------
__global__ __launch_bounds__(256)
void k_pool(const __half* __restrict__ hsm, const float* __restrict__ egl,
            const int* __restrict__ gs, const float* __restrict__ Eg,
            float* __restrict__ hg)
{
    int g = blockIdx.x, ch = blockIdx.y;
    int t = threadIdx.x;
    int c = t & 127, hf = t >> 7;
    int s = gs[g], e = gs[g + 1];
    int per = (e - s + NCH - 1) / NCH;
    int ns = s + ch * per;
    int ne = min(ns + per, e);
    if (ns >= ne) return;
    float inv = 1.f / Eg[g];              // graph non-empty -> Eg > 0
    float acc = 0.f;
    for (int n = ns + hf; n < ne; n += 2)
        acc = fmaf(egl[n], __half2float(hsm[(size_t)n * FD + c]), acc);
    atomicAdd(&hg[g * FD + c], acc * inv);
}

// ---------------- final MLP head ----------------
__global__ __launch_bounds__(64)
void k_head(const float* __restrict__ hg, const float* __restrict__ lin_w,
            const float* __restrict__ lin_b, const float* __restrict__ cls_w,
            const float* __restrict__ cls_b, float* __restrict__ out)
{
    __shared__ float hrow[128];
    __shared__ float tbuf[64];
    int g = blockIdx.x, j = threadIdx.x;
    hrow[j]      = hg[g * FD + j];
    hrow[j + 64] = hg[g * FD + j + 64];
    __syncthreads();
    float a = lin_b[j];
    for (int c = 0; c < 128; ++c) a = fmaf(hrow[c], lin_w[c * 64 + j], a);
    tbuf[j] = a > 0.f ? a : 0.f;
    __syncthreads();
    if (j < OUT) {
        float o = cls_b[j];
        for (int k = 0; k < 64; ++k) o = fmaf(tbuf[k], cls_w[k * OUT + j], o);
        out[g * OUT + j] = o;
    }
}

// ---------------- host launcher ----------------
extern "C" void kernel_launch(void* const* d_in, const int* in_sizes, int n_in,
                              void* d_out, int out_size, void* d_ws, size_t ws_size,
                              hipStream_t stream)
{
    const float* x      = (const float*)d_in[0];
    const int*   ei     = (const int*)d_in[1];
    const int*   src    = ei;
    const int*   dst    = ei + E;
    const int*   batch  = (const int*)d_in[2];
    const float* W1     = (const float*)d_in[3];
    const float* as1    = (const float*)d_in[4];
    const float* ad1    = (const float*)d_in[5];
    const float* b1     = (const float*)d_in[6];
    const float* W2     = (const float*)d_in[7];
    const float* as2    = (const float*)d_in[8];
    const float* ad2    = (const float*)d_in[9];
    const float* b2     = (const float*)d_in[10];
    const float* gate_w = (const float*)d_in[11];
    const float* gate_b = (const float*)d_in[12];
    const float* lin_w  = (const float*)d_in[13];
    const float* lin_b  = (const float*)d_in[14];
    const float* cls_w  = (const float*)d_in[15];
    const float* cls_b  = (const float*)d_in[16];
    float* outp = (float*)d_out;

    char* ws = (char*)d_ws;
    size_t o = 0;
    auto alloc = [&](size_t bytes) -> char* {
        char* p = ws + o;
        o = (o + bytes + 255) & ~(size_t)255;
        return p;
    };

    int*    gs      = (int*)alloc((G + 1) * sizeof(int));
    int*    hist    = (int*)alloc(256 * sizeof(int));
    int*    binbase = (int*)alloc(256 * sizeof(int));
    int*    cursor  = (int*)alloc(256 * sizeof(int));
    int*    off     = (int*)alloc((N + 1) * sizeof(int));
    int*    col     = (int*)alloc((size_t)E * sizeof(int));
    float*  als     = (float*)alloc((size_t)N * H * sizeof(float));
    float*  ald     = (float*)alloc((size_t)N * H * sizeof(float));
    __half* hw      = (__half*)alloc((size_t)N * FD * sizeof(__half));
    __half* h1      = (__half*)alloc((size_t)N * FD * sizeof(__half));
    __half* hsm     = (__half*)alloc((size_t)N * FD * sizeof(__half));
    float*  S1      = (float*)alloc((size_t)G * FD * sizeof(float));
    float*  S2      = (float*)alloc((size_t)G * FD * sizeof(float));
    float*  Eg1     = (float*)alloc(G * sizeof(float));
    float*  Eg2     = (float*)alloc(G * sizeof(float));
    float*  egl     = (float*)alloc((size_t)N * sizeof(float));
    float*  hg      = (float*)alloc((size_t)G * FD * sizeof(float));

    // part[] aliases hw[]: part (E*4B = 6.4MB) is dead after k_fine; hw
    // (N*FD*2B = 12.8MB >= 6.4MB) is first written by k_gemm_al afterwards
    // (stream-ordered).
    unsigned int* part = (unsigned int*)hw;

    int nbN = (N + 255) / 256;   // 196

    // CSR build (two-level partition, no random-address atomics)
    k_zero<<<32, 256, 0, stream>>>(hist, hg, S1, S2, Eg1, Eg2);
    k_graph_starts<<<nbN, 256, 0, stream>>>(batch, gs);
    k_hist<<<NBLK_E, 256, 0, stream>>>(dst, hist);
    k_binscan<<<1, 256, 0, stream>>>(hist, binbase, cursor, off);
    k_partition<<<NBLK_E, 256, 0, stream>>>(src, dst, cursor, part);
    k_fine<<<NBIN, 256, 0, stream>>>(part, binbase, off, col);

    auto run_layer = [&](auto hin, const float* W, const float* a_s,
                         const float* a_d, const float* bias, float* S, float* Eg) {
        k_gemm_al<<<(N + 127) / 128, 256, 0, stream>>>(hin, W, a_s, a_d, hw, als, ald);
        k_agg<<<(N + 3) / 4, 256, 0, stream>>>(hw, als, ald, off, col, bias, h1);
        k_colsum<<<dim3(G, NCH), 256, 0, stream>>>(h1, gs, S);
        k_softmax_gate<<<(N + 3) / 4, 256, 0, stream>>>(h1, batch, S, gate_w, gate_b, hsm, egl, Eg);
        k_pool<<<dim3(G, NCH), 256, 0, stream>>>(hsm, egl, gs, Eg, hg);
    };

    run_layer(x, W1, as1, ad1, b1, S1, Eg1);
    run_layer((const __half*)hsm, W2, as2, ad2, b2, S2, Eg2);

    k_head<<<G, 64, 0, stream>>>(hg, lin_w, lin_b, cls_w, cls_b, outp);
}

// Round 8
// 421.141 us; speedup vs baseline: 2.7699x; 2.7699x over previous
//
#include <hip/hip_runtime.h>
#include <hip/hip_fp16.h>
#include <math.h>

// Problem constants (fixed by the reference)
constexpr int N    = 50000;
constexpr int E    = 1600000;
constexpr int FD   = 128;   // feature dim (in and out of both GAT layers)
constexpr int H    = 4;     // heads
constexpr int G    = 64;    // graphs
constexpr int NCH  = 16;    // node-chunks per graph for parallel reductions
constexpr int OUT  = 10;

// CSR-build partition parameters
constexpr int NBIN   = (N + 255) / 256;        // 196 bins of 256 nodes (bin = dst>>8)
constexpr int EPB    = 4096;                   // edges per partition block
constexpr int NBLK_E = (E + EPB - 1) / EPB;    // 391

#define DEV __device__ __forceinline__

DEV void fma4(float4& a, float s, const float4& w) {
    a.x = fmaf(s, w.x, a.x); a.y = fmaf(s, w.y, a.y);
    a.z = fmaf(s, w.z, a.z); a.w = fmaf(s, w.w, a.w);
}

DEV float lrelu_exp(float z) {             // exp(leaky_relu(z, 0.2))
    return __expf(z > 0.f ? z : 0.2f * z);
}

union HF4 {                                // 4 halfs <-> one 8B word
    float2  f;
    __half2 h[2];
};

DEV void fmah(float4& a, float w, const HF4& u) {
    float2 lo = __half22float2(u.h[0]);
    float2 hi = __half22float2(u.h[1]);
    a.x = fmaf(w, lo.x, a.x); a.y = fmaf(w, lo.y, a.y);
    a.z = fmaf(w, hi.x, a.z); a.w = fmaf(w, hi.y, a.w);
}

DEV float4 load4f(const float* p) { return *(const float4*)p; }
DEV float4 load4f(const __half* p) {
    HF4 u; u.f = *(const float2*)p;
    float2 lo = __half22float2(u.h[0]);
    float2 hi = __half22float2(u.h[1]);
    return make_float4(lo.x, lo.y, hi.x, hi.y);
}

// ---------------- setup kernels ----------------

__global__ void k_zero(int* __restrict__ hist, float* __restrict__ hg,
                       float* __restrict__ S1, float* __restrict__ S2) {
    int i = blockIdx.x * 256 + threadIdx.x;
    if (i < NBIN) hist[i] = 0;
    if (i < G * FD) { hg[i] = 0.f; S1[i] = 0.f; S2[i] = 0.f; }
}

__global__ void k_graph_starts(const int* __restrict__ batch, int* __restrict__ gs) {
    int i = blockIdx.x * 256 + threadIdx.x;
    if (i >= N) return;
    int b  = batch[i];
    int pb = (i == 0) ? -1 : batch[i - 1];
    for (int g = pb + 1; g <= b; ++g) gs[g] = i;
    if (i == N - 1) for (int g = b + 1; g <= G; ++g) gs[g] = N;
}

// Coarse histogram: 196 bins, LDS-aggregated.
__global__ __launch_bounds__(256)
void k_hist(const int* __restrict__ dst, int* __restrict__ hist) {
    __shared__ int lh[NBIN];
    int t = threadIdx.x;
    for (int i = t; i < NBIN; i += 256) lh[i] = 0;
    __syncthreads();
    int base = blockIdx.x * EPB;
#pragma unroll
    for (int j = 0; j < EPB / 256; ++j) {
        int e = base + j * 256 + t;
        if (e < E) atomicAdd(&lh[dst[e] >> 8], 1);
    }
    __syncthreads();
    for (int i = t; i < NBIN; i += 256) if (lh[i]) atomicAdd(&hist[i], lh[i]);
}

// Scan bin totals -> bin bases + partition cursors; also off[N]=E.
__global__ __launch_bounds__(256)
void k_binscan(const int* __restrict__ hist, int* __restrict__ binbase,
               int* __restrict__ cursor, int* __restrict__ off) {
    __shared__ int sh[256];
    int t = threadIdx.x;
    int v = (t < NBIN) ? hist[t] : 0;
    sh[t] = v;
    __syncthreads();
    for (int d = 1; d < 256; d <<= 1) {
        int add = (t >= d) ? sh[t - d] : 0;
        __syncthreads();
        sh[t] += add;
        __syncthreads();
    }
    if (t < NBIN) {
        binbase[t] = sh[t] - v;       // exclusive
        cursor[t]  = sh[t] - v;
    }
    if (t == NBIN - 1) binbase[NBIN] = sh[t];   // == E
    if (t == 0) off[N] = E;
}

// Partition edges into bin-contiguous storage. Pack: src (16b) | dstLocal (8b) << 16.
__global__ __launch_bounds__(256)
void k_partition(const int* __restrict__ src, const int* __restrict__ dst,
                 int* __restrict__ cursor, unsigned int* __restrict__ part) {
    __shared__ int lh[NBIN];
    __shared__ int gb[NBIN];
    int t = threadIdx.x;
    for (int i = t; i < NBIN; i += 256) lh[i] = 0;
    __syncthreads();
    int base = blockIdx.x * EPB;
    unsigned int pk[EPB / 256];
    int          pr[EPB / 256];        // (bin<<16) | rank, or -1
#pragma unroll
    for (int j = 0; j < EPB / 256; ++j) {
        int e = base + j * 256 + t;
        if (e < E) {
            int d = dst[e];
            int b = d >> 8;
            int r = atomicAdd(&lh[b], 1);            // local rank within (block,bin)
            pk[j] = (unsigned)src[e] | ((unsigned)(d & 255) << 16);
            pr[j] = (b << 16) | r;
        } else pr[j] = -1;
    }
    __syncthreads();
    for (int i = t; i < NBIN; i += 256) gb[i] = atomicAdd(&cursor[i], lh[i]);
    __syncthreads();
#pragma unroll
    for (int j = 0; j < EPB / 256; ++j) {
        if (pr[j] >= 0) {
            int b = pr[j] >> 16, r = pr[j] & 0xFFFF;
            part[gb[b] + r] = pk[j];
        }
    }
}

// Fine pass: one block per bin -> per-node CSR offsets + bin-local scatter.
__global__ __launch_bounds__(256)
void k_fine(const unsigned int* __restrict__ part, const int* __restrict__ binbase,
            int* __restrict__ off, int* __restrict__ col) {
    __shared__ int lh[256], lo[256], lc[256];
    int b = blockIdx.x, t = threadIdx.x;
    int s = binbase[b], e = binbase[b + 1];
    lh[t] = 0; lc[t] = 0;
    __syncthreads();
    for (int i = s + t; i < e; i += 256) atomicAdd(&lh[part[i] >> 16], 1);
    __syncthreads();
    int v = lh[t];
    lo[t] = v;
    __syncthreads();
    for (int d = 1; d < 256; d <<= 1) {
        int add = (t >= d) ? lo[t - d] : 0;
        __syncthreads();
        lo[t] += add;
        __syncthreads();
    }
    int ex = lo[t] - v;                 // exclusive scan
    __syncthreads();
    lo[t] = ex;
    __syncthreads();
    int node = b * 256 + t;
    if (node < N) off[node] = s + ex;
    for (int i = s + t; i < e; i += 256) {
        unsigned p = part[i];
        int dl = p >> 16;
        int r = atomicAdd(&lc[dl], 1);
        col[s + lo[dl] + r] = (int)(p & 0xFFFFu);
    }
}

// ---------------- GEMM + attention-logit epilogue ----------------
// Input templated (layer 1: float x, layer 2: fp16 hsm). Output hw fp16.
template <typename TIn>
__global__ __launch_bounds__(256, 2)
void k_gemm_al(const TIn* __restrict__ X, const float* __restrict__ W,
               const float* __restrict__ a_s, const float* __restrict__ a_d,
               __half* __restrict__ hw, float* __restrict__ als, float* __restrict__ ald)
{
    __shared__ float xs[128][128];
    int r0 = blockIdx.x * 128;
    int t  = threadIdx.x;

    for (int i = 0; i < 16; ++i) {
        int f   = i * 256 + t;
        int row = f >> 5;
        int colf = (f & 31) * 4;
        float4 v = make_float4(0.f, 0.f, 0.f, 0.f);
        if (r0 + row < N) v = load4f(X + (size_t)(r0 + row) * FD + colf);
        *(float4*)(&xs[row][colf]) = v;
    }
    __syncthreads();

    int ct = t & 31;
    int rt = t >> 5;
    int c4 = ct * 4;
    int rb = rt * 16;

    float4 acc[16];
#pragma unroll
    for (int r = 0; r < 16; ++r) acc[r] = make_float4(0.f, 0.f, 0.f, 0.f);

    for (int k = 0; k < FD; k += 4) {
        float4 wv0 = *(const float4*)(W + (size_t)(k + 0) * FD + c4);
        float4 wv1 = *(const float4*)(W + (size_t)(k + 1) * FD + c4);
        float4 wv2 = *(const float4*)(W + (size_t)(k + 2) * FD + c4);
        float4 wv3 = *(const float4*)(W + (size_t)(k + 3) * FD + c4);
#pragma unroll
        for (int r = 0; r < 16; ++r) {
            float4 xv = *(const float4*)(&xs[rb + r][k]);
            fma4(acc[r], xv.x, wv0);
            fma4(acc[r], xv.y, wv1);
            fma4(acc[r], xv.z, wv2);
            fma4(acc[r], xv.w, wv3);
        }
    }

    int h  = c4 >> 5;
    int j0 = c4 & 31;
    float as0 = a_s[h * 32 + j0 + 0], as1 = a_s[h * 32 + j0 + 1];
    float as2 = a_s[h * 32 + j0 + 2], as3 = a_s[h * 32 + j0 + 3];
    float ad0 = a_d[h * 32 + j0 + 0], ad1 = a_d[h * 32 + j0 + 1];
    float ad2 = a_d[h * 32 + j0 + 2], ad3 = a_d[h * 32 + j0 + 3];

#pragma unroll
    for (int r = 0; r < 16; ++r) {
        int row = r0 + rb + r;
        bool valid = row < N;
        if (valid) {
            HF4 u;
            u.h[0] = __floats2half2_rn(acc[r].x, acc[r].y);
            u.h[1] = __floats2half2_rn(acc[r].z, acc[r].w);
            *(float2*)(hw + (size_t)row * FD + c4) = u.f;
        }
        float ps = acc[r].x * as0 + acc[r].y * as1 + acc[r].z * as2 + acc[r].w * as3;
        float pd = acc[r].x * ad0 + acc[r].y * ad1 + acc[r].z * ad2 + acc[r].w * ad3;
#pragma unroll
        for (int m = 1; m < 8; m <<= 1) {
            ps += __shfl_xor(ps, m, 64);
            pd += __shfl_xor(pd, m, 64);
        }
        if ((ct & 7) == 0 && valid) {
            als[row * H + h] = ps;
            ald[row * H + h] = pd;
        }
    }
}

// ---------------- fused edge softmax + aggregation ----------------
// One wave per dst node; fp16 rows (256B): 32 lanes x 8B cover one row, so
// the wave processes TWO edges per step (lane halves q=0/1) x4 unrolled ->
// 8 gathers in flight. f32 accumulate; h1 written fp16.
__global__ __launch_bounds__(256)
void k_agg(const __half* __restrict__ hw, const float* __restrict__ als,
           const float* __restrict__ ald, const int* __restrict__ off,
           const int* __restrict__ col, const float* __restrict__ bias,
           __half* __restrict__ h1)
{
    int n = blockIdx.x * 4 + (threadIdx.x >> 6);
    if (n >= N) return;
    int l = threadIdx.x & 63;
    int q = l >> 5;                 // half: edge parity
    int p = l & 31;                 // lane within half: owns cols 4p..4p+3
    int h = p >> 3;                 // head of my columns
    float adn = ald[n * H + h];

    // self-loop: half 0 only
    float4 acc = make_float4(0.f, 0.f, 0.f, 0.f);
    float sumw;
    {
        float w = q ? 0.f : lrelu_exp(als[n * H + h] + adn);
        HF4 u; u.f = *(const float2*)(hw + (size_t)n * FD + 4 * p);
        fmah(acc, w, u);
        sumw = w;
    }

    int ib = off[n];
    int deg = off[n + 1] - ib;
    int j = 0;
    for (; j + 8 <= deg; j += 8) {          // 4 steps x 2 halves
        int s0 = col[ib + j + 0 + q];
        int s1 = col[ib + j + 2 + q];
        int s2 = col[ib + j + 4 + q];
        int s3 = col[ib + j + 6 + q];
        float z0 = als[s0 * H + h];
        float z1 = als[s1 * H + h];
        float z2 = als[s2 * H + h];
        float z3 = als[s3 * H + h];
        HF4 u0; u0.f = *(const float2*)(hw + (size_t)s0 * FD + 4 * p);
        HF4 u1; u1.f = *(const float2*)(hw + (size_t)s1 * FD + 4 * p);
        HF4 u2; u2.f = *(const float2*)(hw + (size_t)s2 * FD + 4 * p);
        HF4 u3; u3.f = *(const float2*)(hw + (size_t)s3 * FD + 4 * p);
        float w0 = lrelu_exp(z0 + adn);
        float w1 = lrelu_exp(z1 + adn);
        float w2 = lrelu_exp(z2 + adn);
        float w3 = lrelu_exp(z3 + adn);
        fmah(acc, w0, u0);
        fmah(acc, w1, u1);
        fmah(acc, w2, u2);
        fmah(acc, w3, u3);
        sumw += w0 + w1 + w2 + w3;
    }
    for (; j + 2 <= deg; j += 2) {          // 1 step x 2 halves
        int s = col[ib + j + q];
        float w = lrelu_exp(als[s * H + h] + adn);
        HF4 u; u.f = *(const float2*)(hw + (size_t)s * FD + 4 * p);
        fmah(acc, w, u);
        sumw += w;
    }
    if (j < deg) {                          // odd leftover: half 0 only
        int s = q ? n : col[ib + j];
        float w = q ? 0.f : lrelu_exp(als[s * H + h] + adn);
        HF4 u; u.f = *(const float2*)(hw + (size_t)s * FD + 4 * p);
        fmah(acc, w, u);
        sumw += w;
    }

    // merge halves (lane l <-> l+32 hold the same columns)
    acc.x += __shfl_xor(acc.x, 32, 64);
    acc.y += __shfl_xor(acc.y, 32, 64);
    acc.z += __shfl_xor(acc.z, 32, 64);
    acc.w += __shfl_xor(acc.w, 32, 64);
    sumw  += __shfl_xor(sumw,  32, 64);

    if (q == 0) {
        float inv = 1.f / sumw;
        float4 b4 = *(const float4*)(bias + 4 * p);
        float4 o;
        o.x = fmaf(acc.x, inv, b4.x);
        o.y = fmaf(acc.y, inv, b4.y);
        o.z = fmaf(acc.z, inv, b4.z);
        o.w = fmaf(acc.w, inv, b4.w);
        o.x = o.x > 0.f ? o.x : 0.f;
        o.y = o.y > 0.f ? o.y : 0.f;
        o.z = o.z > 0.f ? o.z : 0.f;
        o.w = o.w > 0.f ? o.w : 0.f;
        HF4 u;
        u.h[0] = __floats2half2_rn(o.x, o.y);
        u.h[1] = __floats2half2_rn(o.z, o.w);
        *(float2*)(h1 + (size_t)n * FD + 4 * p) = u.f;
    }
}

// ---------------- per-graph column exp-sums (no max-shift; h1 >= 0 bounded) ----------------
__global__ __launch_bounds__(256)
void k_colsum(const __half* __restrict__ h1, const int* __restrict__ gs,
              float* __restrict__ S)
{
    int g = blockIdx.x, ch = blockIdx.y;
    int t = threadIdx.x;
    int c = t & 127, hf = t >> 7;
    int s = gs[g], e = gs[g + 1];
    int per = (e - s + NCH - 1) / NCH;
    int ns = s + ch * per;
    int ne = min(ns + per, e);
    float sum = 0.f;
    for (int n = ns + hf; n < ne; n += 2)
        sum += __expf(__half2float(h1[(size_t)n * FD + c]));
    if (sum > 0.f) atomicAdd(&S[g * FD + c], sum);
}

// ---------------- node softmax-normalize + gate logit exp (no atomics) ----------------
__global__ __launch_bounds__(256)
void k_softmax_gate(const __half* __restrict__ h1, const int* __restrict__ batch,
                    const float* __restrict__ S, const float* __restrict__ gw,
                    const float* __restrict__ gb, __half* __restrict__ hsm,
                    float* __restrict__ egl)
{
    int n = blockIdx.x * 4 + (threadIdx.x >> 6);
    if (n >= N) return;
    int l = threadIdx.x & 63;
    int g = batch[n];
    float2 hv = __half22float2(*(const __half2*)(h1 + (size_t)n * FD + 2 * l));
    float2 sv = *(const float2*)(S + g * FD + 2 * l);
    float vx = __expf(hv.x) / sv.x;
    float vy = __expf(hv.y) / sv.y;
    *(__half2*)(hsm + (size_t)n * FD + 2 * l) = __floats2half2_rn(vx, vy);
    float p = vx * gw[2 * l] + vy * gw[2 * l + 1];
#pragma unroll
    for (int m = 1; m < 64; m <<= 1) p += __shfl_xor(p, m, 64);
    if (l == 0) egl[n] = __expf(p + gb[0]);   // no max-shift: p is tiny
}

// ---------------- per-graph gate exp-sum (one block per graph, no atomics) ----------------
__global__ __launch_bounds__(256)
void k_gatesum(const float* __restrict__ egl, const int* __restrict__ gs,
               float* __restrict__ Eg)
{
    __shared__ float red[4];
    int g = blockIdx.x;
    int s = gs[g], e = gs[g + 1];
    int t = threadIdx.x;
    float sum = 0.f;
    for (int i = s + t; i < e; i += 256) sum += egl[i];
#pragma unroll
    for (int mk = 1; mk < 64; mk <<= 1) sum += __shfl_xor(sum, mk, 64);
    if ((t & 63) == 0) red[t >> 6] = sum;
    __syncthreads();
    if (t == 0) Eg[g] = red[0] + red[1] + red[2] + red[3];
}

// ---------------- gated pooling (chunked, atomic accumulate into hg) ----------------
__global__ __launch_bounds__(256)
void k_pool(const __half* __restrict__ hsm, const float* __restrict__ egl,
            const int* __restrict__ gs, const float* __restrict__ Eg,
            float* __restrict__ hg)
{
    int g = blockIdx.x, ch = blockIdx.y;
    int t = threadIdx.x;
    int c = t & 127, hf = t >> 7;
    int s = gs[g], e = gs[g + 1];
    int per = (e - s + NCH - 1) / NCH;
    int ns = s + ch * per;
    int ne = min(ns + per, e);
    if (ns >= ne) return;
    float inv = 1.f / Eg[g];              // graph non-empty -> Eg > 0
    float acc = 0.f;
    for (int n = ns + hf; n < ne; n += 2)
        acc = fmaf(egl[n], __half2float(hsm[(size_t)n * FD + c]), acc);
    atomicAdd(&hg[g * FD + c], acc * inv);
}

// ---------------- final MLP head ----------------
__global__ __launch_bounds__(64)
void k_head(const float* __restrict__ hg, const float* __restrict__ lin_w,
            const float* __restrict__ lin_b, const float* __restrict__ cls_w,
            const float* __restrict__ cls_b, float* __restrict__ out)
{
    __shared__ float hrow[128];
    __shared__ float tbuf[64];
    int g = blockIdx.x, j = threadIdx.x;
    hrow[j]      = hg[g * FD + j];
    hrow[j + 64] = hg[g * FD + j + 64];
    __syncthreads();
    float a = lin_b[j];
    for (int c = 0; c < 128; ++c) a = fmaf(hrow[c], lin_w[c * 64 + j], a);
    tbuf[j] = a > 0.f ? a : 0.f;
    __syncthreads();
    if (j < OUT) {
        float o = cls_b[j];
        for (int k = 0; k < 64; ++k) o = fmaf(tbuf[k], cls_w[k * OUT + j], o);
        out[g * OUT + j] = o;
    }
}

// ---------------- host launcher ----------------
extern "C" void kernel_launch(void* const* d_in, const int* in_sizes, int n_in,
                              void* d_out, int out_size, void* d_ws, size_t ws_size,
                              hipStream_t stream)
{
    const float* x      = (const float*)d_in[0];
    const int*   ei     = (const int*)d_in[1];
    const int*   src    = ei;
    const int*   dst    = ei + E;
    const int*   batch  = (const int*)d_in[2];
    const float* W1     = (const float*)d_in[3];
    const float* as1    = (const float*)d_in[4];
    const float* ad1    = (const float*)d_in[5];
    const float* b1     = (const float*)d_in[6];
    const float* W2     = (const float*)d_in[7];
    const float* as2    = (const float*)d_in[8];
    const float* ad2    = (const float*)d_in[9];
    const float* b2     = (const float*)d_in[10];
    const float* gate_w = (const float*)d_in[11];
    const float* gate_b = (const float*)d_in[12];
    const float* lin_w  = (const float*)d_in[13];
    const float* lin_b  = (const float*)d_in[14];
    const float* cls_w  = (const float*)d_in[15];
    const float* cls_b  = (const float*)d_in[16];
    float* outp = (float*)d_out;

    char* ws = (char*)d_ws;
    size_t o = 0;
    auto alloc = [&](size_t bytes) -> char* {
        char* p = ws + o;
        o = (o + bytes + 255) & ~(size_t)255;
        return p;
    };

    int*    gs      = (int*)alloc((G + 1) * sizeof(int));
    int*    hist    = (int*)alloc(256 * sizeof(int));
    int*    binbase = (int*)alloc(256 * sizeof(int));
    int*    cursor  = (int*)alloc(256 * sizeof(int));
    int*    off     = (int*)alloc((N + 1) * sizeof(int));
    int*    col     = (int*)alloc((size_t)E * sizeof(int));
    float*  als     = (float*)alloc((size_t)N * H * sizeof(float));
    float*  ald     = (float*)alloc((size_t)N * H * sizeof(float));
    __half* hw      = (__half*)alloc((size_t)N * FD * sizeof(__half));
    __half* h1      = (__half*)alloc((size_t)N * FD * sizeof(__half));
    __half* hsm     = (__half*)alloc((size_t)N * FD * sizeof(__half));
    float*  S1      = (float*)alloc((size_t)G * FD * sizeof(float));
    float*  S2      = (float*)alloc((size_t)G * FD * sizeof(float));
    float*  Eg      = (float*)alloc(G * sizeof(float));
    float*  egl     = (float*)alloc((size_t)N * sizeof(float));
    float*  hg      = (float*)alloc((size_t)G * FD * sizeof(float));

    // part[] aliases hw[]: part (E*4B = 6.4MB) is dead after k_fine; hw
    // (N*FD*2B = 12.8MB >= 6.4MB) is first written by k_gemm_al afterwards
    // (stream-ordered).
    unsigned int* part = (unsigned int*)hw;

    int nbN = (N + 255) / 256;   // 196

    // CSR build (two-level partition, no random-address atomics)
    k_zero<<<32, 256, 0, stream>>>(hist, hg, S1, S2);
    k_graph_starts<<<nbN, 256, 0, stream>>>(batch, gs);
    k_hist<<<NBLK_E, 256, 0, stream>>>(dst, hist);
    k_binscan<<<1, 256, 0, stream>>>(hist, binbase, cursor, off);
    k_partition<<<NBLK_E, 256, 0, stream>>>(src, dst, cursor, part);
    k_fine<<<NBIN, 256, 0, stream>>>(part, binbase, off, col);

    auto run_layer = [&](auto hin, const float* W, const float* a_s,
                         const float* a_d, const float* bias, float* S) {
        k_gemm_al<<<(N + 127) / 128, 256, 0, stream>>>(hin, W, a_s, a_d, hw, als, ald);
        k_agg<<<(N + 3) / 4, 256, 0, stream>>>(hw, als, ald, off, col, bias, h1);
        k_colsum<<<dim3(G, NCH), 256, 0, stream>>>(h1, gs, S);
        k_softmax_gate<<<(N + 3) / 4, 256, 0, stream>>>(h1, batch, S, gate_w, gate_b, hsm, egl);
        k_gatesum<<<G, 256, 0, stream>>>(egl, gs, Eg);
        k_pool<<<dim3(G, NCH), 256, 0, stream>>>(hsm, egl, gs, Eg, hg);
    };

    run_layer(x, W1, as1, ad1, b1, S1);
    run_layer((const __half*)hsm, W2, as2, ad2, b2, S2);

    k_head<<<G, 64, 0, stream>>>(hg, lin_w, lin_b, cls_w, cls_b, outp);
}

// Round 9
// 401.983 us; speedup vs baseline: 2.9019x; 1.0477x over previous
//
#include <hip/hip_runtime.h>
#include <hip/hip_fp16.h>
#include <math.h>

// Problem constants (fixed by the reference)
constexpr int N    = 50000;
constexpr int E    = 1600000;
constexpr int FD   = 128;   // feature dim (in and out of both GAT layers)
constexpr int H    = 4;     // heads
constexpr int G    = 64;    // graphs
constexpr int NCH  = 16;    // node-chunks per graph for parallel reductions
constexpr int OUT  = 10;

// CSR-build partition parameters
constexpr int NBIN   = (N + 255) / 256;        // 196 bins of 256 nodes (bin = dst>>8)
constexpr int EPB    = 4096;                   // edges per partition block
constexpr int NBLK_E = (E + EPB - 1) / EPB;    // 391

#define DEV __device__ __forceinline__

DEV void fma4(float4& a, float s, const float4& w) {
    a.x = fmaf(s, w.x, a.x); a.y = fmaf(s, w.y, a.y);
    a.z = fmaf(s, w.z, a.z); a.w = fmaf(s, w.w, a.w);
}

DEV float lrelu_exp(float z) {             // exp(leaky_relu(z, 0.2))
    return __expf(z > 0.f ? z : 0.2f * z);
}

union HF4 {                                // 4 halfs <-> one 8B word
    float2  f;
    __half2 h[2];
};

DEV void fmah(float4& a, float w, const HF4& u) {
    float2 lo = __half22float2(u.h[0]);
    float2 hi = __half22float2(u.h[1]);
    a.x = fmaf(w, lo.x, a.x); a.y = fmaf(w, lo.y, a.y);
    a.z = fmaf(w, hi.x, a.z); a.w = fmaf(w, hi.y, a.w);
}

DEV float4 load4f(const float* p) { return *(const float4*)p; }
DEV float4 load4f(const __half* p) {
    HF4 u; u.f = *(const float2*)p;
    float2 lo = __half22float2(u.h[0]);
    float2 hi = __half22float2(u.h[1]);
    return make_float4(lo.x, lo.y, hi.x, hi.y);
}

// ---------------- setup: zero workspace + graph starts (merged) ----------------
__global__ void k_setup(const int* __restrict__ batch, int* __restrict__ gs,
                        int* __restrict__ hist, float* __restrict__ hg,
                        float* __restrict__ S1, float* __restrict__ S2,
                        float* __restrict__ Eg) {
    int i = blockIdx.x * 256 + threadIdx.x;
    if (i < NBIN) hist[i] = 0;
    if (i < 2 * G * FD) hg[i] = 0.f;         // both layers' pooled accumulators
    if (i < G * FD) { S1[i] = 0.f; S2[i] = 0.f; }
    if (i < 2 * G) Eg[i] = 0.f;
    if (i < N) {
        int b  = batch[i];
        int pb = (i == 0) ? -1 : batch[i - 1];
        for (int g = pb + 1; g <= b; ++g) gs[g] = i;
        if (i == N - 1) for (int g = b + 1; g <= G; ++g) gs[g] = N;
    }
}

// Coarse histogram: 196 bins, LDS-aggregated.
__global__ __launch_bounds__(256)
void k_hist(const int* __restrict__ dst, int* __restrict__ hist) {
    __shared__ int lh[NBIN];
    int t = threadIdx.x;
    for (int i = t; i < NBIN; i += 256) lh[i] = 0;
    __syncthreads();
    int base = blockIdx.x * EPB;
#pragma unroll
    for (int j = 0; j < EPB / 256; ++j) {
        int e = base + j * 256 + t;
        if (e < E) atomicAdd(&lh[dst[e] >> 8], 1);
    }
    __syncthreads();
    for (int i = t; i < NBIN; i += 256) if (lh[i]) atomicAdd(&hist[i], lh[i]);
}

// Scan bin totals -> bin bases + partition cursors; also off[N]=E.
__global__ __launch_bounds__(256)
void k_binscan(const int* __restrict__ hist, int* __restrict__ binbase,
               int* __restrict__ cursor, int* __restrict__ off) {
    __shared__ int sh[256];
    int t = threadIdx.x;
    int v = (t < NBIN) ? hist[t] : 0;
    sh[t] = v;
    __syncthreads();
    for (int d = 1; d < 256; d <<= 1) {
        int add = (t >= d) ? sh[t - d] : 0;
        __syncthreads();
        sh[t] += add;
        __syncthreads();
    }
    if (t < NBIN) {
        binbase[t] = sh[t] - v;       // exclusive
        cursor[t]  = sh[t] - v;
    }
    if (t == NBIN - 1) binbase[NBIN] = sh[t];   // == E
    if (t == 0) off[N] = E;
}

// Partition edges into bin-contiguous storage. Pack: src (16b) | dstLocal (8b) << 16.
__global__ __launch_bounds__(256)
void k_partition(const int* __restrict__ src, const int* __restrict__ dst,
                 int* __restrict__ cursor, unsigned int* __restrict__ part) {
    __shared__ int lh[NBIN];
    __shared__ int gb[NBIN];
    int t = threadIdx.x;
    for (int i = t; i < NBIN; i += 256) lh[i] = 0;
    __syncthreads();
    int base = blockIdx.x * EPB;
    unsigned int pk[EPB / 256];
    int          pr[EPB / 256];        // (bin<<16) | rank, or -1
#pragma unroll
    for (int j = 0; j < EPB / 256; ++j) {
        int e = base + j * 256 + t;
        if (e < E) {
            int d = dst[e];
            int b = d >> 8;
            int r = atomicAdd(&lh[b], 1);            // local rank within (block,bin)
            pk[j] = (unsigned)src[e] | ((unsigned)(d & 255) << 16);
            pr[j] = (b << 16) | r;
        } else pr[j] = -1;
    }
    __syncthreads();
    for (int i = t; i < NBIN; i += 256) gb[i] = atomicAdd(&cursor[i], lh[i]);
    __syncthreads();
#pragma unroll
    for (int j = 0; j < EPB / 256; ++j) {
        if (pr[j] >= 0) {
            int b = pr[j] >> 16, r = pr[j] & 0xFFFF;
            part[gb[b] + r] = pk[j];
        }
    }
}

// Fine pass: one block per bin -> per-node CSR offsets + bin-local scatter.
__global__ __launch_bounds__(256)
void k_fine(const unsigned int* __restrict__ part, const int* __restrict__ binbase,
            int* __restrict__ off, int* __restrict__ col) {
    __shared__ int lh[256], lo[256], lc[256];
    int b = blockIdx.x, t = threadIdx.x;
    int s = binbase[b], e = binbase[b + 1];
    lh[t] = 0; lc[t] = 0;
    __syncthreads();
    for (int i = s + t; i < e; i += 256) atomicAdd(&lh[part[i] >> 16], 1);
    __syncthreads();
    int v = lh[t];
    lo[t] = v;
    __syncthreads();
    for (int d = 1; d < 256; d <<= 1) {
        int add = (t >= d) ? lo[t - d] : 0;
        __syncthreads();
        lo[t] += add;
        __syncthreads();
    }
    int ex = lo[t] - v;                 // exclusive scan
    __syncthreads();
    lo[t] = ex;
    __syncthreads();
    int node = b * 256 + t;
    if (node < N) off[node] = s + ex;
    for (int i = s + t; i < e; i += 256) {
        unsigned p = part[i];
        int dl = p >> 16;
        int r = atomicAdd(&lc[dl], 1);
        col[s + lo[dl] + r] = (int)(p & 0xFFFFu);
    }
}

// ---------------- GEMM + attention-logit epilogue ----------------
// Input templated (layer 1: float x, layer 2: fp16 hsm). Output hw fp16.
template <typename TIn>
__global__ __launch_bounds__(256, 2)
void k_gemm_al(const TIn* __restrict__ X, const float* __restrict__ W,
               const float* __restrict__ a_s, const float* __restrict__ a_d,
               __half* __restrict__ hw, float* __restrict__ als, float* __restrict__ ald)
{
    __shared__ float xs[128][128];
    int r0 = blockIdx.x * 128;
    int t  = threadIdx.x;

    for (int i = 0; i < 16; ++i) {
        int f   = i * 256 + t;
        int row = f >> 5;
        int colf = (f & 31) * 4;
        float4 v = make_float4(0.f, 0.f, 0.f, 0.f);
        if (r0 + row < N) v = load4f(X + (size_t)(r0 + row) * FD + colf);
        *(float4*)(&xs[row][colf]) = v;
    }
    __syncthreads();

    int ct = t & 31;
    int rt = t >> 5;
    int c4 = ct * 4;
    int rb = rt * 16;

    float4 acc[16];
#pragma unroll
    for (int r = 0; r < 16; ++r) acc[r] = make_float4(0.f, 0.f, 0.f, 0.f);

    for (int k = 0; k < FD; k += 4) {
        float4 wv0 = *(const float4*)(W + (size_t)(k + 0) * FD + c4);
        float4 wv1 = *(const float4*)(W + (size_t)(k + 1) * FD + c4);
        float4 wv2 = *(const float4*)(W + (size_t)(k + 2) * FD + c4);
        float4 wv3 = *(const float4*)(W + (size_t)(k + 3) * FD + c4);
#pragma unroll
        for (int r = 0; r < 16; ++r) {
            float4 xv = *(const float4*)(&xs[rb + r][k]);
            fma4(acc[r], xv.x, wv0);
            fma4(acc[r], xv.y, wv1);
            fma4(acc[r], xv.z, wv2);
            fma4(acc[r], xv.w, wv3);
        }
    }

    int h  = c4 >> 5;
    int j0 = c4 & 31;
    float as0 = a_s[h * 32 + j0 + 0], as1 = a_s[h * 32 + j0 + 1];
    float as2 = a_s[h * 32 + j0 + 2], as3 = a_s[h * 32 + j0 + 3];
    float ad0 = a_d[h * 32 + j0 + 0], ad1 = a_d[h * 32 + j0 + 1];
    float ad2 = a_d[h * 32 + j0 + 2], ad3 = a_d[h * 32 + j0 + 3];

#pragma unroll
    for (int r = 0; r < 16; ++r) {
        int row = r0 + rb + r;
        bool valid = row < N;
        if (valid) {
            HF4 u;
            u.h[0] = __floats2half2_rn(acc[r].x, acc[r].y);
            u.h[1] = __floats2half2_rn(acc[r].z, acc[r].w);
            *(float2*)(hw + (size_t)row * FD + c4) = u.f;
        }
        float ps = acc[r].x * as0 + acc[r].y * as1 + acc[r].z * as2 + acc[r].w * as3;
        float pd = acc[r].x * ad0 + acc[r].y * ad1 + acc[r].z * ad2 + acc[r].w * ad3;
#pragma unroll
        for (int m = 1; m < 8; m <<= 1) {
            ps += __shfl_xor(ps, m, 64);
            pd += __shfl_xor(pd, m, 64);
        }
        if ((ct & 7) == 0 && valid) {
            als[row * H + h] = ps;
            ald[row * H + h] = pd;
        }
    }
}

// ---------------- fused edge softmax + aggregation ----------------
// One wave per dst node; fp16 rows (256B): 32 lanes x 8B cover one row, so
// the wave processes TWO edges per step (lane halves q=0/1) x4 unrolled ->
// 8 gathers in flight. f32 accumulate; h1 written fp16.
__global__ __launch_bounds__(256)
void k_agg(const __half* __restrict__ hw, const float* __restrict__ als,
           const float* __restrict__ ald, const int* __restrict__ off,
           const int* __restrict__ col, const float* __restrict__ bias,
           __half* __restrict__ h1)
{
    int n = blockIdx.x * 4 + (threadIdx.x >> 6);
    if (n >= N) return;
    int l = threadIdx.x & 63;
    int q = l >> 5;                 // half: edge parity
    int p = l & 31;                 // lane within half: owns cols 4p..4p+3
    int h = p >> 3;                 // head of my columns
    float adn = ald[n * H + h];

    // self-loop: half 0 only
    float4 acc = make_float4(0.f, 0.f, 0.f, 0.f);
    float sumw;
    {
        float w = q ? 0.f : lrelu_exp(als[n * H + h] + adn);
        HF4 u; u.f = *(const float2*)(hw + (size_t)n * FD + 4 * p);
        fmah(acc, w, u);
        sumw = w;
    }

    int ib = off[n];
    int deg = off[n + 1] - ib;
    int j = 0;
    for (; j + 8 <= deg; j += 8) {          // 4 steps x 2 halves
        int s0 = col[ib + j + 0 + q];
        int s1 = col[ib + j + 2 + q];
        int s2 = col[ib + j + 4 + q];
        int s3 = col[ib + j + 6 + q];
        float z0 = als[s0 * H + h];
        float z1 = als[s1 * H + h];
        float z2 = als[s2 * H + h];
        float z3 = als[s3 * H + h];
        HF4 u0; u0.f = *(const float2*)(hw + (size_t)s0 * FD + 4 * p);
        HF4 u1; u1.f = *(const float2*)(hw + (size_t)s1 * FD + 4 * p);
        HF4 u2; u2.f = *(const float2*)(hw + (size_t)s2 * FD + 4 * p);
        HF4 u3; u3.f = *(const float2*)(hw + (size_t)s3 * FD + 4 * p);
        float w0 = lrelu_exp(z0 + adn);
        float w1 = lrelu_exp(z1 + adn);
        float w2 = lrelu_exp(z2 + adn);
        float w3 = lrelu_exp(z3 + adn);
        fmah(acc, w0, u0);
        fmah(acc, w1, u1);
        fmah(acc, w2, u2);
        fmah(acc, w3, u3);
        sumw += w0 + w1 + w2 + w3;
    }
    for (; j + 2 <= deg; j += 2) {          // 1 step x 2 halves
        int s = col[ib + j + q];
        float w = lrelu_exp(als[s * H + h] + adn);
        HF4 u; u.f = *(const float2*)(hw + (size_t)s * FD + 4 * p);
        fmah(acc, w, u);
        sumw += w;
    }
    if (j < deg) {                          // odd leftover: half 0 only
        int s = q ? n : col[ib + j];
        float w = q ? 0.f : lrelu_exp(als[s * H + h] + adn);
        HF4 u; u.f = *(const float2*)(hw + (size_t)s * FD + 4 * p);
        fmah(acc, w, u);
        sumw += w;
    }

    // merge halves (lane l <-> l+32 hold the same columns)
    acc.x += __shfl_xor(acc.x, 32, 64);
    acc.y += __shfl_xor(acc.y, 32, 64);
    acc.z += __shfl_xor(acc.z, 32, 64);
    acc.w += __shfl_xor(acc.w, 32, 64);
    sumw  += __shfl_xor(sumw,  32, 64);

    if (q == 0) {
        float inv = 1.f / sumw;
        float4 b4 = *(const float4*)(bias + 4 * p);
        float4 o;
        o.x = fmaf(acc.x, inv, b4.x);
        o.y = fmaf(acc.y, inv, b4.y);
        o.z = fmaf(acc.z, inv, b4.z);
        o.w = fmaf(acc.w, inv, b4.w);
        o.x = o.x > 0.f ? o.x : 0.f;
        o.y = o.y > 0.f ? o.y : 0.f;
        o.z = o.z > 0.f ? o.z : 0.f;
        o.w = o.w > 0.f ? o.w : 0.f;
        HF4 u;
        u.h[0] = __floats2half2_rn(o.x, o.y);
        u.h[1] = __floats2half2_rn(o.z, o.w);
        *(float2*)(h1 + (size_t)n * FD + 4 * p) = u.f;
    }
}

// ---------------- per-graph column exp-sums (vectorized 8B/lane) ----------------
// Block = (g,ch): 8 row-phases x 32 col-threads x 4 cols. LDS cross-phase
// reduce -> 128 atomics per block.
__global__ __launch_bounds__(256)
void k_colsum(const __half* __restrict__ h1, const int* __restrict__ gs,
              float* __restrict__ S)
{
    __shared__ float sh[256][4];
    int g = blockIdx.x, ch = blockIdx.y;
    int t = threadIdx.x;
    int p = t & 31, hf = t >> 5;
    int s = gs[g], e = gs[g + 1];
    int per = (e - s + NCH - 1) / NCH;
    int ns = s + ch * per;
    int ne = min(ns + per, e);
    if (ns >= ne) return;                 // uniform per block
    float4 acc = make_float4(0.f, 0.f, 0.f, 0.f);
    for (int n = ns + hf; n < ne; n += 8) {
        HF4 u; u.f = *(const float2*)(h1 + (size_t)n * FD + 4 * p);
        float2 lo = __half22float2(u.h[0]);
        float2 hi = __half22float2(u.h[1]);
        acc.x += __expf(lo.x); acc.y += __expf(lo.y);
        acc.z += __expf(hi.x); acc.w += __expf(hi.y);
    }
    sh[t][0] = acc.x; sh[t][1] = acc.y; sh[t][2] = acc.z; sh[t][3] = acc.w;
    __syncthreads();
    if (t < 32) {
        float4 a = make_float4(0.f, 0.f, 0.f, 0.f);
#pragma unroll
        for (int j = 0; j < 8; ++j) {
            a.x += sh[j * 32 + t][0]; a.y += sh[j * 32 + t][1];
            a.z += sh[j * 32 + t][2]; a.w += sh[j * 32 + t][3];
        }
        atomicAdd(&S[g * FD + 4 * t + 0], a.x);
        atomicAdd(&S[g * FD + 4 * t + 1], a.y);
        atomicAdd(&S[g * FD + 4 * t + 2], a.z);
        atomicAdd(&S[g * FD + 4 * t + 3], a.w);
    }
}

// ---------------- node softmax-normalize + gate logit exp (8B/lane) ----------------
// Half-wave (32 lanes) per node, 4 cols/lane.
__global__ __launch_bounds__(256)
void k_softmax_gate(const __half* __restrict__ h1, const int* __restrict__ batch,
                    const float* __restrict__ S, const float* __restrict__ gw,
                    const float* __restrict__ gb, __half* __restrict__ hsm,
                    float* __restrict__ egl)
{
    int n = blockIdx.x * 8 + (threadIdx.x >> 5);
    if (n >= N) return;
    int p = threadIdx.x & 31;
    int g = batch[n];
    HF4 u; u.f = *(const float2*)(h1 + (size_t)n * FD + 4 * p);
    float2 lo = __half22float2(u.h[0]);
    float2 hi = __half22float2(u.h[1]);
    float4 sv = *(const float4*)(S + g * FD + 4 * p);
    float vx = __expf(lo.x) / sv.x;
    float vy = __expf(lo.y) / sv.y;
    float vz = __expf(hi.x) / sv.z;
    float vw = __expf(hi.y) / sv.w;
    HF4 o;
    o.h[0] = __floats2half2_rn(vx, vy);
    o.h[1] = __floats2half2_rn(vz, vw);
    *(float2*)(hsm + (size_t)n * FD + 4 * p) = o.f;
    float4 gv = *(const float4*)(gw + 4 * p);
    float pl = vx * gv.x + vy * gv.y + vz * gv.z + vw * gv.w;
#pragma unroll
    for (int m = 1; m < 32; m <<= 1) pl += __shfl_xor(pl, m, 32);
    if (p == 0) egl[n] = __expf(pl + gb[0]);   // no max-shift: pl is tiny
}

// ---------------- gated pooling, unnormalized + Eg accumulate ----------------
// hgl/Egl are per-layer; k_head divides by Eg at the end.
__global__ __launch_bounds__(256)
void k_pool(const __half* __restrict__ hsm, const float* __restrict__ egl,
            const int* __restrict__ gs, float* __restrict__ hgl,
            float* __restrict__ Egl)
{
    __shared__ float sh[256][4];
    __shared__ float se[8];
    int g = blockIdx.x, ch = blockIdx.y;
    int t = threadIdx.x;
    int p = t & 31, hf = t >> 5;
    int s = gs[g], e = gs[g + 1];
    int per = (e - s + NCH - 1) / NCH;
    int ns = s + ch * per;
    int ne = min(ns + per, e);
    if (ns >= ne) return;                 // uniform per block
    float4 acc = make_float4(0.f, 0.f, 0.f, 0.f);
    float esum = 0.f;
    for (int n = ns + hf; n < ne; n += 8) {
        float eg = egl[n];
        if (p == 0) esum += eg;
        HF4 u; u.f = *(const float2*)(hsm + (size_t)n * FD + 4 * p);
        float2 lo = __half22float2(u.h[0]);
        float2 hi = __half22float2(u.h[1]);
        acc.x = fmaf(eg, lo.x, acc.x); acc.y = fmaf(eg, lo.y, acc.y);
        acc.z = fmaf(eg, hi.x, acc.z); acc.w = fmaf(eg, hi.y, acc.w);
    }
    sh[t][0] = acc.x; sh[t][1] = acc.y; sh[t][2] = acc.z; sh[t][3] = acc.w;
    if (p == 0) se[hf] = esum;
    __syncthreads();
    if (t < 32) {
        float4 a = make_float4(0.f, 0.f, 0.f, 0.f);
#pragma unroll
        for (int j = 0; j < 8; ++j) {
            a.x += sh[j * 32 + t][0]; a.y += sh[j * 32 + t][1];
            a.z += sh[j * 32 + t][2]; a.w += sh[j * 32 + t][3];
        }
        atomicAdd(&hgl[g * FD + 4 * t + 0], a.x);
        atomicAdd(&hgl[g * FD + 4 * t + 1], a.y);
        atomicAdd(&hgl[g * FD + 4 * t + 2], a.z);
        atomicAdd(&hgl[g * FD + 4 * t + 3], a.w);
    } else if (t == 32) {
        float es = 0.f;
#pragma unroll
        for (int j = 0; j < 8; ++j) es += se[j];
        atomicAdd(&Egl[g], es);
    }
}

// ---------------- final MLP head (normalizes pooled sums by Eg) ----------------
__global__ __launch_bounds__(64)
void k_head(const float* __restrict__ hg, const float* __restrict__ Eg,
            const float* __restrict__ lin_w, const float* __restrict__ lin_b,
            const float* __restrict__ cls_w, const float* __restrict__ cls_b,
            float* __restrict__ out)
{
    __shared__ float hrow[128];
    __shared__ float tbuf[64];
    int g = blockIdx.x, j = threadIdx.x;
    float e1 = Eg[g], e2 = Eg[G + g];
    float i1 = e1 > 0.f ? 1.f / e1 : 0.f;
    float i2 = e2 > 0.f ? 1.f / e2 : 0.f;
    const float* hg1 = hg;
    const float* hg2 = hg + G * FD;
    hrow[j]      = hg1[g * FD + j] * i1      + hg2[g * FD + j] * i2;
    hrow[j + 64] = hg1[g * FD + j + 64] * i1 + hg2[g * FD + j + 64] * i2;
    __syncthreads();
    float a = lin_b[j];
    for (int c = 0; c < 128; ++c) a = fmaf(hrow[c], lin_w[c * 64 + j], a);
    tbuf[j] = a > 0.f ? a : 0.f;
    __syncthreads();
    if (j < OUT) {
        float o = cls_b[j];
        for (int k = 0; k < 64; ++k) o = fmaf(tbuf[k], cls_w[k * OUT + j], o);
        out[g * OUT + j] = o;
    }
}

// ---------------- host launcher ----------------
extern "C" void kernel_launch(void* const* d_in, const int* in_sizes, int n_in,
                              void* d_out, int out_size, void* d_ws, size_t ws_size,
                              hipStream_t stream)
{
    const float* x      = (const float*)d_in[0];
    const int*   ei     = (const int*)d_in[1];
    const int*   src    = ei;
    const int*   dst    = ei + E;
    const int*   batch  = (const int*)d_in[2];
    const float* W1     = (const float*)d_in[3];
    const float* as1    = (const float*)d_in[4];
    const float* ad1    = (const float*)d_in[5];
    const float* b1     = (const float*)d_in[6];
    const float* W2     = (const float*)d_in[7];
    const float* as2    = (const float*)d_in[8];
    const float* ad2    = (const float*)d_in[9];
    const float* b2     = (const float*)d_in[10];
    const float* gate_w = (const float*)d_in[11];
    const float* gate_b = (const float*)d_in[12];
    const float* lin_w  = (const float*)d_in[13];
    const float* lin_b  = (const float*)d_in[14];
    const float* cls_w  = (const float*)d_in[15];
    const float* cls_b  = (const float*)d_in[16];
    float* outp = (float*)d_out;

    char* ws = (char*)d_ws;
    size_t o = 0;
    auto alloc = [&](size_t bytes) -> char* {
        char* p = ws + o;
        o = (o + bytes + 255) & ~(size_t)255;
        return p;
    };

    int*    gs      = (int*)alloc((G + 1) * sizeof(int));
    int*    hist    = (int*)alloc(256 * sizeof(int));
    int*    binbase = (int*)alloc(256 * sizeof(int));
    int*    cursor  = (int*)alloc(256 * sizeof(int));
    int*    off     = (int*)alloc((N + 1) * sizeof(int));
    int*    col     = (int*)alloc((size_t)E * sizeof(int));
    float*  als     = (float*)alloc((size_t)N * H * sizeof(float));
    float*  ald     = (float*)alloc((size_t)N * H * sizeof(float));
    __half* hw      = (__half*)alloc((size_t)N * FD * sizeof(__half));
    __half* h1      = (__half*)alloc((size_t)N * FD * sizeof(__half));
    __half* hsm     = (__half*)alloc((size_t)N * FD * sizeof(__half));
    float*  S1      = (float*)alloc((size_t)G * FD * sizeof(float));
    float*  S2      = (float*)alloc((size_t)G * FD * sizeof(float));
    float*  Eg      = (float*)alloc((size_t)2 * G * sizeof(float));
    float*  egl     = (float*)alloc((size_t)N * sizeof(float));
    float*  hg      = (float*)alloc((size_t)2 * G * FD * sizeof(float));

    // part[] aliases hw[]: part (E*4B = 6.4MB) is dead after k_fine; hw
    // (N*FD*2B = 12.8MB >= 6.4MB) is first written by k_gemm_al afterwards
    // (stream-ordered).
    unsigned int* part = (unsigned int*)hw;

    int nbN = (N + 255) / 256;   // 196

    // Setup + CSR build (two-level partition, no random-address atomics)
    k_setup<<<nbN, 256, 0, stream>>>(batch, gs, hist, hg, S1, S2, Eg);
    k_hist<<<NBLK_E, 256, 0, stream>>>(dst, hist);
    k_binscan<<<1, 256, 0, stream>>>(hist, binbase, cursor, off);
    k_partition<<<NBLK_E, 256, 0, stream>>>(src, dst, cursor, part);
    k_fine<<<NBIN, 256, 0, stream>>>(part, binbase, off, col);

    auto run_layer = [&](auto hin, const float* W, const float* a_s,
                         const float* a_d, const float* bias, float* S,
                         float* hgl, float* Egl) {
        k_gemm_al<<<(N + 127) / 128, 256, 0, stream>>>(hin, W, a_s, a_d, hw, als, ald);
        k_agg<<<(N + 3) / 4, 256, 0, stream>>>(hw, als, ald, off, col, bias, h1);
        k_colsum<<<dim3(G, NCH), 256, 0, stream>>>(h1, gs, S);
        k_softmax_gate<<<(N + 7) / 8, 256, 0, stream>>>(h1, batch, S, gate_w, gate_b, hsm, egl);
        k_pool<<<dim3(G, NCH), 256, 0, stream>>>(hsm, egl, gs, hgl, Egl);
    };

    run_layer(x, W1, as1, ad1, b1, S1, hg, Eg);
    run_layer((const __half*)hsm, W2, as2, ad2, b2, S2, hg + G * FD, Eg + G);

    k_head<<<G, 64, 0, stream>>>(hg, Eg, lin_w, lin_b, cls_w, cls_b, outp);
}

// Round 11
// 401.028 us; speedup vs baseline: 2.9088x; 1.0024x over previous
//
#include <hip/hip_runtime.h>
#include <hip/hip_fp16.h>
#include <math.h>

// Problem constants (fixed by the reference)
constexpr int N    = 50000;
constexpr int E    = 1600000;
constexpr int FD   = 128;   // feature dim (in and out of both GAT layers)
constexpr int H    = 4;     // heads
constexpr int G    = 64;    // graphs
constexpr int NCH  = 16;    // node-chunks per graph for parallel reductions
constexpr int OUT  = 10;

// CSR-build partition parameters
constexpr int NBIN   = (N + 255) / 256;        // 196 bins of 256 nodes (bin = dst>>8)
constexpr int EPB    = 4096;                   // edges per partition block
constexpr int NBLK_E = (E + EPB - 1) / EPB;    // 391

constexpr int LDH = 136;   // padded LDS row stride in halves (272B -> 2-way bank alias, free)

#define DEV __device__ __forceinline__

typedef _Float16 h8 __attribute__((ext_vector_type(8)));
typedef float f32x4 __attribute__((ext_vector_type(4)));

DEV float lrelu_exp(float z) {             // exp(leaky_relu(z, 0.2))
    return __expf(z > 0.f ? z : 0.2f * z);
}

union HF4 {                                // 4 halfs <-> one 8B word
    float2  f;
    __half2 h[2];
};

DEV void fmah(float4& a, float w, const HF4& u) {
    float2 lo = __half22float2(u.h[0]);
    float2 hi = __half22float2(u.h[1]);
    a.x = fmaf(w, lo.x, a.x); a.y = fmaf(w, lo.y, a.y);
    a.z = fmaf(w, hi.x, a.z); a.w = fmaf(w, hi.y, a.w);
}

// ---------------- setup: zero workspace + graph starts (merged) ----------------
__global__ void k_setup(const int* __restrict__ batch, int* __restrict__ gs,
                        int* __restrict__ hist, float* __restrict__ hg,
                        float* __restrict__ S1, float* __restrict__ S2,
                        float* __restrict__ Eg) {
    int i = blockIdx.x * 256 + threadIdx.x;
    if (i < NBIN) hist[i] = 0;
    if (i < 2 * G * FD) hg[i] = 0.f;         // both layers' pooled accumulators
    if (i < G * FD) { S1[i] = 0.f; S2[i] = 0.f; }
    if (i < 2 * G) Eg[i] = 0.f;
    if (i < N) {
        int b  = batch[i];
        int pb = (i == 0) ? -1 : batch[i - 1];
        for (int g = pb + 1; g <= b; ++g) gs[g] = i;
        if (i == N - 1) for (int g = b + 1; g <= G; ++g) gs[g] = N;
    }
}

// ---------------- W prep: fp16 transpose + fused logit vectors ----------------
// Wt[c][k] = fp16(W[k][c]);  WSD[k][h*2+0/1] = sum_j W[k][h*32+j] * a_{s,d}[h][j]
__global__ __launch_bounds__(256)
void k_wprep(const float* __restrict__ W, const float* __restrict__ a_s,
             const float* __restrict__ a_d, _Float16* __restrict__ Wt,
             float* __restrict__ WSD)
{
    int t = threadIdx.x;
    for (int pass = 0; pass < 64; ++pass) {
        int idx = pass * 256 + t;
        int k = idx >> 7, c = idx & 127;
        Wt[c * FD + k] = (_Float16)W[idx];
    }
    if (t < FD) {
        for (int h = 0; h < H; ++h) {
            float ss = 0.f, sd = 0.f;
            for (int j = 0; j < 32; ++j) {
                float wv = W[t * FD + h * 32 + j];
                ss = fmaf(wv, a_s[h * 32 + j], ss);
                sd = fmaf(wv, a_d[h * 32 + j], sd);
            }
            WSD[t * 8 + h * 2]     = ss;
            WSD[t * 8 + h * 2 + 1] = sd;
        }
    }
}

// Coarse histogram: 196 bins, LDS-aggregated.
__global__ __launch_bounds__(256)
void k_hist(const int* __restrict__ dst, int* __restrict__ hist) {
    __shared__ int lh[NBIN];
    int t = threadIdx.x;
    for (int i = t; i < NBIN; i += 256) lh[i] = 0;
    __syncthreads();
    int base = blockIdx.x * EPB;
#pragma unroll
    for (int j = 0; j < EPB / 256; ++j) {
        int e = base + j * 256 + t;
        if (e < E) atomicAdd(&lh[dst[e] >> 8], 1);
    }
    __syncthreads();
    for (int i = t; i < NBIN; i += 256) if (lh[i]) atomicAdd(&hist[i], lh[i]);
}

// Scan bin totals -> bin bases + partition cursors; also off[N]=E.
__global__ __launch_bounds__(256)
void k_binscan(const int* __restrict__ hist, int* __restrict__ binbase,
               int* __restrict__ cursor, int* __restrict__ off) {
    __shared__ int sh[256];
    int t = threadIdx.x;
    int v = (t < NBIN) ? hist[t] : 0;
    sh[t] = v;
    __syncthreads();
    for (int d = 1; d < 256; d <<= 1) {
        int add = (t >= d) ? sh[t - d] : 0;
        __syncthreads();
        sh[t] += add;
        __syncthreads();
    }
    if (t < NBIN) {
        binbase[t] = sh[t] - v;       // exclusive
        cursor[t]  = sh[t] - v;
    }
    if (t == NBIN - 1) binbase[NBIN] = sh[t];   // == E
    if (t == 0) off[N] = E;
}

// Partition edges into bin-contiguous storage. Pack: src (16b) | dstLocal (8b) << 16.
__global__ __launch_bounds__(256)
void k_partition(const int* __restrict__ src, const int* __restrict__ dst,
                 int* __restrict__ cursor, unsigned int* __restrict__ part) {
    __shared__ int lh[NBIN];
    __shared__ int gb[NBIN];
    int t = threadIdx.x;
    for (int i = t; i < NBIN; i += 256) lh[i] = 0;
    __syncthreads();
    int base = blockIdx.x * EPB;
    unsigned int pk[EPB / 256];
    int          pr[EPB / 256];        // (bin<<16) | rank, or -1
#pragma unroll
    for (int j = 0; j < EPB / 256; ++j) {
        int e = base + j * 256 + t;
        if (e < E) {
            int d = dst[e];
            int b = d >> 8;
            int r = atomicAdd(&lh[b], 1);            // local rank within (block,bin)
            pk[j] = (unsigned)src[e] | ((unsigned)(d & 255) << 16);
            pr[j] = (b << 16) | r;
        } else pr[j] = -1;
    }
    __syncthreads();
    for (int i = t; i < NBIN; i += 256) gb[i] = atomicAdd(&cursor[i], lh[i]);
    __syncthreads();
#pragma unroll
    for (int j = 0; j < EPB / 256; ++j) {
        if (pr[j] >= 0) {
            int b = pr[j] >> 16, r = pr[j] & 0xFFFF;
            part[gb[b] + r] = pk[j];
        }
    }
}

// Fine pass: one block per bin -> per-node CSR offsets + bin-local scatter.
__global__ __launch_bounds__(256)
void k_fine(const unsigned int* __restrict__ part, const int* __restrict__ binbase,
            int* __restrict__ off, int* __restrict__ col) {
    __shared__ int lh[256], lo[256], lc[256];
    int b = blockIdx.x, t = threadIdx.x;
    int s = binbase[b], e = binbase[b + 1];
    lh[t] = 0; lc[t] = 0;
    __syncthreads();
    for (int i = s + t; i < e; i += 256) atomicAdd(&lh[part[i] >> 16], 1);
    __syncthreads();
    int v = lh[t];
    lo[t] = v;
    __syncthreads();
    for (int d = 1; d < 256; d <<= 1) {
        int add = (t >= d) ? lo[t - d] : 0;
        __syncthreads();
        lo[t] += add;
        __syncthreads();
    }
    int ex = lo[t] - v;                 // exclusive scan
    __syncthreads();
    lo[t] = ex;
    __syncthreads();
    int node = b * 256 + t;
    if (node < N) off[node] = s + ex;
    for (int i = s + t; i < e; i += 256) {
        unsigned p = part[i];
        int dl = p >> 16;
        int r = atomicAdd(&lc[dl], 1);
        col[s + lo[dl] + r] = (int)(p & 0xFFFFu);
    }
}

// ---------------- MFMA GEMM (fp16 in, f32 acc) + attention logits ----------------
// Block: 256 threads / 4 waves; tile 128 rows x 128 cols, K=128 in one LDS load.
// Wave w owns rows 32w..32w+31 (2 row-tiles of 16) x all 8 col-tiles.
// mfma_f32_16x16x32_f16 layouts: A row=l&15, k=(l>>4)*8+i (contiguous);
// B col=l&15, k contiguous via transposed Wt; C/D col=l&15, row=(l>>4)*4+reg.
// als/ald computed as X @ WSD (fused logit vectors) by a dedicated per-row loop.
template <typename TIn>
__global__ __launch_bounds__(256, 2)
void k_gemm_mfma(const TIn* __restrict__ X, const _Float16* __restrict__ Wt,
                 const float* __restrict__ WSD, __half* __restrict__ hw,
                 float* __restrict__ als, float* __restrict__ ald)
{
    __shared__ _Float16 Xh[128 * LDH];
    __shared__ _Float16 Wl[128 * LDH];
    __shared__ float    wsd[128 * 8];
    int r0 = blockIdx.x * 128;
    int t  = threadIdx.x;

    // stage X (cvt to fp16 if f32 source; zero-fill OOB rows) + Wt copy
#pragma unroll
    for (int pass = 0; pass < 8; ++pass) {
        int idx  = pass * 2048 + t * 8;    // half index into 128x128
        int row  = idx >> 7;
        int colh = idx & 127;
        h8 v = {};
        if (r0 + row < N) {
            if constexpr (sizeof(TIn) == 4) {
                const float4* sp = (const float4*)(X + (size_t)(r0 + row) * FD + colh);
                float4 f0 = sp[0], f1 = sp[1];
                v[0] = (_Float16)f0.x; v[1] = (_Float16)f0.y;
                v[2] = (_Float16)f0.z; v[3] = (_Float16)f0.w;
                v[4] = (_Float16)f1.x; v[5] = (_Float16)f1.y;
                v[6] = (_Float16)f1.z; v[7] = (_Float16)f1.w;
            } else {
                v = *(const h8*)((const _Float16*)X + (size_t)(r0 + row) * FD + colh);
            }
        }
        *(h8*)&Xh[row * LDH + colh] = v;
        *(h8*)&Wl[row * LDH + colh] = *(const h8*)(Wt + idx);
    }
    if (t < 128) {
        *(float4*)&wsd[t * 8]     = *(const float4*)(WSD + t * 8);
        *(float4*)&wsd[t * 8 + 4] = *(const float4*)(WSD + t * 8 + 4);
    }
    __syncthreads();

    // attention logits: row r, thread-pair half p handles heads 2p, 2p+1 (s+d)
    {
        int row = t >> 1, p = t & 1;
        float s0 = 0.f, s1 = 0.f, s2 = 0.f, s3 = 0.f;
        for (int j = 0; j < FD; j += 8) {
            h8 xv = *(h8*)&Xh[row * LDH + j];
#pragma unroll
            for (int u = 0; u < 8; ++u) {
                float xf = (float)xv[u];
                float4 wq = *(float4*)&wsd[(j + u) * 8 + p * 4];
                s0 = fmaf(xf, wq.x, s0); s1 = fmaf(xf, wq.y, s1);
                s2 = fmaf(xf, wq.z, s2); s3 = fmaf(xf, wq.w, s3);
            }
        }
        int grow = r0 + row;
        if (grow < N) {
            als[grow * H + 2 * p + 0] = s0;
            ald[grow * H + 2 * p + 0] = s1;
            als[grow * H + 2 * p + 1] = s2;
            ald[grow * H + 2 * p + 1] = s3;
        }
    }

    // MFMA main
    int w = t >> 6, l = t & 63;
    int lr = l & 15, kg = l >> 4;
    int koff = kg * 8;

    h8 a[2][4];
#pragma unroll
    for (int rt = 0; rt < 2; ++rt)
#pragma unroll
        for (int kk = 0; kk < 4; ++kk)
            a[rt][kk] = *(h8*)&Xh[(w * 32 + rt * 16 + lr) * LDH + kk * 32 + koff];

    f32x4 acc[2][8] = {};
#pragma unroll
    for (int ct = 0; ct < 8; ++ct) {
        h8 b0 = *(h8*)&Wl[(ct * 16 + lr) * LDH + 0 * 32 + koff];
        h8 b1 = *(h8*)&Wl[(ct * 16 + lr) * LDH + 1 * 32 + koff];
        h8 b2 = *(h8*)&Wl[(ct * 16 + lr) * LDH + 2 * 32 + koff];
        h8 b3 = *(h8*)&Wl[(ct * 16 + lr) * LDH + 3 * 32 + koff];
#pragma unroll
        for (int rt = 0; rt < 2; ++rt) {
            f32x4 c = acc[rt][ct];
            c = __builtin_amdgcn_mfma_f32_16x16x32_f16(a[rt][0], b0, c, 0, 0, 0);
            c = __builtin_amdgcn_mfma_f32_16x16x32_f16(a[rt][1], b1, c, 0, 0, 0);
            c = __builtin_amdgcn_mfma_f32_16x16x32_f16(a[rt][2], b2, c, 0, 0, 0);
            c = __builtin_amdgcn_mfma_f32_16x16x32_f16(a[rt][3], b3, c, 0, 0, 0);
            acc[rt][ct] = c;
        }
    }

    // store hw fp16: row = r0+32w+16rt+4kg+reg, col = 16ct+lr
#pragma unroll
    for (int rt = 0; rt < 2; ++rt) {
        int rbase = r0 + w * 32 + rt * 16 + kg * 4;
#pragma unroll
        for (int reg = 0; reg < 4; ++reg) {
            int grow = rbase + reg;
            if (grow < N) {
#pragma unroll
                for (int ct = 0; ct < 8; ++ct)
                    hw[(size_t)grow * FD + ct * 16 + lr] = __float2half(acc[rt][ct][reg]);
            }
        }
    }
}

// ---------------- fused edge softmax + aggregation ----------------
// One wave per dst node; fp16 rows (256B): 32 lanes x 8B cover one row, so
// the wave processes TWO edges per step (lane halves q=0/1) x4 unrolled ->
// 8 gathers in flight. f32 accumulate; h1 written fp16.
__global__ __launch_bounds__(256)
void k_agg(const __half* __restrict__ hw, const float* __restrict__ als,
           const float* __restrict__ ald, const int* __restrict__ off,
           const int* __restrict__ col, const float* __restrict__ bias,
           __half* __restrict__ h1)
{
    int n = blockIdx.x * 4 + (threadIdx.x >> 6);
    if (n >= N) return;
    int l = threadIdx.x & 63;
    int q = l >> 5;                 // half: edge parity
    int p = l & 31;                 // lane within half: owns cols 4p..4p+3
    int h = p >> 3;                 // head of my columns
    float adn = ald[n * H + h];

    // self-loop: half 0 only
    float4 acc = make_float4(0.f, 0.f, 0.f, 0.f);
    float sumw;
    {
        float w = q ? 0.f : lrelu_exp(als[n * H + h] + adn);
        HF4 u; u.f = *(const float2*)(hw + (size_t)n * FD + 4 * p);
        fmah(acc, w, u);
        sumw = w;
    }

    int ib = off[n];
    int deg = off[n + 1] - ib;
    int j = 0;
    for (; j + 8 <= deg; j += 8) {          // 4 steps x 2 halves
        int s0 = col[ib + j + 0 + q];
        int s1 = col[ib + j + 2 + q];
        int s2 = col[ib + j + 4 + q];
        int s3 = col[ib + j + 6 + q];
        float z0 = als[s0 * H + h];
        float z1 = als[s1 * H + h];
        float z2 = als[s2 * H + h];
        float z3 = als[s3 * H + h];
        HF4 u0; u0.f = *(const float2*)(hw + (size_t)s0 * FD + 4 * p);
        HF4 u1; u1.f = *(const float2*)(hw + (size_t)s1 * FD + 4 * p);
        HF4 u2; u2.f = *(const float2*)(hw + (size_t)s2 * FD + 4 * p);
        HF4 u3; u3.f = *(const float2*)(hw + (size_t)s3 * FD + 4 * p);
        float w0 = lrelu_exp(z0 + adn);
        float w1 = lrelu_exp(z1 + adn);
        float w2 = lrelu_exp(z2 + adn);
        float w3 = lrelu_exp(z3 + adn);
        fmah(acc, w0, u0);
        fmah(acc, w1, u1);
        fmah(acc, w2, u2);
        fmah(acc, w3, u3);
        sumw += w0 + w1 + w2 + w3;
    }
    for (; j + 2 <= deg; j += 2) {          // 1 step x 2 halves
        int s = col[ib + j + q];
        float w = lrelu_exp(als[s * H + h] + adn);
        HF4 u; u.f = *(const float2*)(hw + (size_t)s * FD + 4 * p);
        fmah(acc, w, u);
        sumw += w;
    }
    if (j < deg) {                          // odd leftover: half 0 only
        int s = q ? n : col[ib + j];
        float w = q ? 0.f : lrelu_exp(als[s * H + h] + adn);
        HF4 u; u.f = *(const float2*)(hw + (size_t)s * FD + 4 * p);
        fmah(acc, w, u);
        sumw += w;
    }

    // merge halves (lane l <-> l+32 hold the same columns)
    acc.x += __shfl_xor(acc.x, 32, 64);
    acc.y += __shfl_xor(acc.y, 32, 64);
    acc.z += __shfl_xor(acc.z, 32, 64);
    acc.w += __shfl_xor(acc.w, 32, 64);
    sumw  += __shfl_xor(sumw,  32, 64);

    if (q == 0) {
        float inv = 1.f / sumw;
        float4 b4 = *(const float4*)(bias + 4 * p);
        float4 o;
        o.x = fmaf(acc.x, inv, b4.x);
        o.y = fmaf(acc.y, inv, b4.y);
        o.z = fmaf(acc.z, inv, b4.z);
        o.w = fmaf(acc.w, inv, b4.w);
        o.x = o.x > 0.f ? o.x : 0.f;
        o.y = o.y > 0.f ? o.y : 0.f;
        o.z = o.z > 0.f ? o.z : 0.f;
        o.w = o.w > 0.f ? o.w : 0.f;
        HF4 u;
        u.h[0] = __floats2half2_rn(o.x, o.y);
        u.h[1] = __floats2half2_rn(o.z, o.w);
        *(float2*)(h1 + (size_t)n * FD + 4 * p) = u.f;
    }
}

// ---------------- per-graph column exp-sums (vectorized 8B/lane) ----------------
__global__ __launch_bounds__(256)
void k_colsum(const __half* __restrict__ h1, const int* __restrict__ gs,
              float* __restrict__ S)
{
    __shared__ float sh[256][4];
    int g = blockIdx.x, ch = blockIdx.y;
    int t = threadIdx.x;
    int p = t & 31, hf = t >> 5;
    int s = gs[g], e = gs[g + 1];
    int per = (e - s + NCH - 1) / NCH;
    int ns = s + ch * per;
    int ne = min(ns + per, e);
    if (ns >= ne) return;                 // uniform per block
    float4 acc = make_float4(0.f, 0.f, 0.f, 0.f);
    for (int n = ns + hf; n < ne; n += 8) {
        HF4 u; u.f = *(const float2*)(h1 + (size_t)n * FD + 4 * p);
        float2 lo = __half22float2(u.h[0]);
        float2 hi = __half22float2(u.h[1]);
        acc.x += __expf(lo.x); acc.y += __expf(lo.y);
        acc.z += __expf(hi.x); acc.w += __expf(hi.y);
    }
    sh[t][0] = acc.x; sh[t][1] = acc.y; sh[t][2] = acc.z; sh[t][3] = acc.w;
    __syncthreads();
    if (t < 32) {
        float4 a = make_float4(0.f, 0.f, 0.f, 0.f);
#pragma unroll
        for (int j = 0; j < 8; ++j) {
            a.x += sh[j * 32 + t][0]; a.y += sh[j * 32 + t][1];
            a.z += sh[j * 32 + t][2]; a.w += sh[j * 32 + t][3];
        }
        atomicAdd(&S[g * FD + 4 * t + 0], a.x);
        atomicAdd(&S[g * FD + 4 * t + 1], a.y);
        atomicAdd(&S[g * FD + 4 * t + 2], a.z);
        atomicAdd(&S[g * FD + 4 * t + 3], a.w);
    }
}

// ---------------- node softmax-normalize + gate logit exp (8B/lane) ----------------
__global__ __launch_bounds__(256)
void k_softmax_gate(const __half* __restrict__ h1, const int* __restrict__ batch,
                    const float* __restrict__ S, const float* __restrict__ gw,
                    const float* __restrict__ gb, __half* __restrict__ hsm,
                    float* __restrict__ egl)
{
    int n = blockIdx.x * 8 + (threadIdx.x >> 5);
    if (n >= N) return;
    int p = threadIdx.x & 31;
    int g = batch[n];
    HF4 u; u.f = *(const float2*)(h1 + (size_t)n * FD + 4 * p);
    float2 lo = __half22float2(u.h[0]);
    float2 hi = __half22float2(u.h[1]);
    float4 sv = *(const float4*)(S + g * FD + 4 * p);
    float vx = __expf(lo.x) / sv.x;
    float vy = __expf(lo.y) / sv.y;
    float vz = __expf(hi.x) / sv.z;
    float vw = __expf(hi.y) / sv.w;
    HF4 o;
    o.h[0] = __floats2half2_rn(vx, vy);
    o.h[1] = __floats2half2_rn(vz, vw);
    *(float2*)(hsm + (size_t)n * FD + 4 * p) = o.f;
    float4 gv = *(const float4*)(gw + 4 * p);
    float pl = vx * gv.x + vy * gv.y + vz * gv.z + vw * gv.w;
#pragma unroll
    for (int m = 1; m < 32; m <<= 1) pl += __shfl_xor(pl, m, 32);
    if (p == 0) egl[n] = __expf(pl + gb[0]);   // no max-shift: pl is tiny
}

// ---------------- gated pooling, unnormalized + Eg accumulate ----------------
__global__ __launch_bounds__(256)
void k_pool(const __half* __restrict__ hsm, const float* __restrict__ egl,
            const int* __restrict__ gs, float* __restrict__ hgl,
            float* __restrict__ Egl)
{
    __shared__ float sh[256][4];
    __shared__ float se[8];
    int g = blockIdx.x, ch = blockIdx.y;
    int t = threadIdx.x;
    int p = t & 31, hf = t >> 5;
    int s = gs[g], e = gs[g + 1];
    int per = (e - s + NCH - 1) / NCH;
    int ns = s + ch * per;
    int ne = min(ns + per, e);
    if (ns >= ne) return;                 // uniform per block
    float4 acc = make_float4(0.f, 0.f, 0.f, 0.f);
    float esum = 0.f;
    for (int n = ns + hf; n < ne; n += 8) {
        float eg = egl[n];
        if (p == 0) esum += eg;
        HF4 u; u.f = *(const float2*)(hsm + (size_t)n * FD + 4 * p);
        float2 lo = __half22float2(u.h[0]);
        float2 hi = __half22float2(u.h[1]);
        acc.x = fmaf(eg, lo.x, acc.x); acc.y = fmaf(eg, lo.y, acc.y);
        acc.z = fmaf(eg, hi.x, acc.z); acc.w = fmaf(eg, hi.y, acc.w);
    }
    sh[t][0] = acc.x; sh[t][1] = acc.y; sh[t][2] = acc.z; sh[t][3] = acc.w;
    if (p == 0) se[hf] = esum;
    __syncthreads();
    if (t < 32) {
        float4 a = make_float4(0.f, 0.f, 0.f, 0.f);
#pragma unroll
        for (int j = 0; j < 8; ++j) {
            a.x += sh[j * 32 + t][0]; a.y += sh[j * 32 + t][1];
            a.z += sh[j * 32 + t][2]; a.w += sh[j * 32 + t][3];
        }
        atomicAdd(&hgl[g * FD + 4 * t + 0], a.x);
        atomicAdd(&hgl[g * FD + 4 * t + 1], a.y);
        atomicAdd(&hgl[g * FD + 4 * t + 2], a.z);
        atomicAdd(&hgl[g * FD + 4 * t + 3], a.w);
    } else if (t == 32) {
        float es = 0.f;
#pragma unroll
        for (int j = 0; j < 8; ++j) es += se[j];
        atomicAdd(&Egl[g], es);
    }
}

// ---------------- final MLP head (normalizes pooled sums by Eg) ----------------
__global__ __launch_bounds__(64)
void k_head(const float* __restrict__ hg, const float* __restrict__ Eg,
            const float* __restrict__ lin_w, const float* __restrict__ lin_b,
            const float* __restrict__ cls_w, const float* __restrict__ cls_b,
            float* __restrict__ out)
{
    __shared__ float hrow[128];
    __shared__ float tbuf[64];
    int g = blockIdx.x, j = threadIdx.x;
    float e1 = Eg[g], e2 = Eg[G + g];
    float i1 = e1 > 0.f ? 1.f / e1 : 0.f;
    float i2 = e2 > 0.f ? 1.f / e2 : 0.f;
    const float* hg1 = hg;
    const float* hg2 = hg + G * FD;
    hrow[j]      = hg1[g * FD + j] * i1      + hg2[g * FD + j] * i2;
    hrow[j + 64] = hg1[g * FD + j + 64] * i1 + hg2[g * FD + j + 64] * i2;
    __syncthreads();
    float a = lin_b[j];
    for (int c = 0; c < 128; ++c) a = fmaf(hrow[c], lin_w[c * 64 + j], a);
    tbuf[j] = a > 0.f ? a : 0.f;
    __syncthreads();
    if (j < OUT) {
        float o = cls_b[j];
        for (int k = 0; k < 64; ++k) o = fmaf(tbuf[k], cls_w[k * OUT + j], o);
        out[g * OUT + j] = o;
    }
}

// ---------------- host launcher ----------------
extern "C" void kernel_launch(void* const* d_in, const int* in_sizes, int n_in,
                              void* d_out, int out_size, void* d_ws, size_t ws_size,
                              hipStream_t stream)
{
    const float* x      = (const float*)d_in[0];
    const int*   ei     = (const int*)d_in[1];
    const int*   src    = ei;
    const int*   dst    = ei + E;
    const int*   batch  = (const int*)d_in[2];
    const float* W1     = (const float*)d_in[3];
    const float* as1    = (const float*)d_in[4];
    const float* ad1    = (const float*)d_in[5];
    const float* b1     = (const float*)d_in[6];
    const float* W2     = (const float*)d_in[7];
    const float* as2    = (const float*)d_in[8];
    const float* ad2    = (const float*)d_in[9];
    const float* b2     = (const float*)d_in[10];
    const float* gate_w = (const float*)d_in[11];
    const float* gate_b = (const float*)d_in[12];
    const float* lin_w  = (const float*)d_in[13];
    const float* lin_b  = (const float*)d_in[14];
    const float* cls_w  = (const float*)d_in[15];
    const float* cls_b  = (const float*)d_in[16];
    float* outp = (float*)d_out;

    char* ws = (char*)d_ws;
    size_t o = 0;
    auto alloc = [&](size_t bytes) -> char* {
        char* p = ws + o;
        o = (o + bytes + 255) & ~(size_t)255;
        return p;
    };

    int*      gs      = (int*)alloc((G + 1) * sizeof(int));
    int*      hist    = (int*)alloc(256 * sizeof(int));
    int*      binbase = (int*)alloc(256 * sizeof(int));
    int*      cursor  = (int*)alloc(256 * sizeof(int));
    int*      off     = (int*)alloc((N + 1) * sizeof(int));
    int*      col     = (int*)alloc((size_t)E * sizeof(int));
    float*    als     = (float*)alloc((size_t)N * H * sizeof(float));
    float*    ald     = (float*)alloc((size_t)N * H * sizeof(float));
    __half*   hw      = (__half*)alloc((size_t)N * FD * sizeof(__half));
    __half*   h1      = (__half*)alloc((size_t)N * FD * sizeof(__half));
    __half*   hsm     = (__half*)alloc((size_t)N * FD * sizeof(__half));
    float*    S1      = (float*)alloc((size_t)G * FD * sizeof(float));
    float*    S2      = (float*)alloc((size_t)G * FD * sizeof(float));
    float*    Eg      = (float*)alloc((size_t)2 * G * sizeof(float));
    float*    egl     = (float*)alloc((size_t)N * sizeof(float));
    float*    hg      = (float*)alloc((size_t)2 * G * FD * sizeof(float));
    _Float16* Wt1     = (_Float16*)alloc((size_t)FD * FD * sizeof(_Float16));
    _Float16* Wt2     = (_Float16*)alloc((size_t)FD * FD * sizeof(_Float16));
    float*    WSD1    = (float*)alloc((size_t)FD * 8 * sizeof(float));
    float*    WSD2    = (float*)alloc((size_t)FD * 8 * sizeof(float));

    // part[] aliases hw[]: part (E*4B = 6.4MB) is dead after k_fine; hw
    // (N*FD*2B = 12.8MB >= 6.4MB) is first written by k_gemm_mfma afterwards
    // (stream-ordered).
    unsigned int* part = (unsigned int*)hw;

    int nbN = (N + 255) / 256;   // 196

    // W prep (independent) + setup + CSR build
    k_wprep<<<1, 256, 0, stream>>>(W1, as1, ad1, Wt1, WSD1);
    k_wprep<<<1, 256, 0, stream>>>(W2, as2, ad2, Wt2, WSD2);
    k_setup<<<nbN, 256, 0, stream>>>(batch, gs, hist, hg, S1, S2, Eg);
    k_hist<<<NBLK_E, 256, 0, stream>>>(dst, hist);
    k_binscan<<<1, 256, 0, stream>>>(hist, binbase, cursor, off);
    k_partition<<<NBLK_E, 256, 0, stream>>>(src, dst, cursor, part);
    k_fine<<<NBIN, 256, 0, stream>>>(part, binbase, off, col);

    auto run_layer = [&](auto hin, const _Float16* Wt, const float* WSD,
                         const float* bias, float* S, float* hgl, float* Egl) {
        k_gemm_mfma<<<(N + 127) / 128, 256, 0, stream>>>(hin, Wt, WSD, hw, als, ald);
        k_agg<<<(N + 3) / 4, 256, 0, stream>>>(hw, als, ald, off, col, bias, h1);
        k_colsum<<<dim3(G, NCH), 256, 0, stream>>>(h1, gs, S);
        k_softmax_gate<<<(N + 7) / 8, 256, 0, stream>>>(h1, batch, S, gate_w, gate_b, hsm, egl);
        k_pool<<<dim3(G, NCH), 256, 0, stream>>>(hsm, egl, gs, hgl, Egl);
    };

    run_layer(x, Wt1, WSD1, b1, S1, hg, Eg);
    run_layer((const __half*)hsm, Wt2, WSD2, b2, S2, hg + G * FD, Eg + G);

    k_head<<<G, 64, 0, stream>>>(hg, Eg, lin_w, lin_b, cls_w, cls_b, outp);
}